// Round 6
// baseline (23133.789 us; speedup 1.0000x reference)
//
#include <hip/hip_runtime.h>
#include <cstdint>
#include <cstddef>

#define BB 128    // batch
#define TT 80     // seq
#define EE 100    // emb dim
#define EP 128    // padded emb dim
#define UU 2048   // units
#define G3 6144   // 3*UU
#define PLANE (BB * UU)   // 262144 elements, one gate pre-activation plane

typedef __bf16 bf16x8 __attribute__((ext_vector_type(8)));
typedef float f32x4 __attribute__((ext_vector_type(4)));

static __device__ __forceinline__ unsigned short f2bf(float x) {
  union { float f; unsigned int u; } a; a.f = x;
  unsigned int r = a.u + 0x7fffu + ((a.u >> 16) & 1u);  // RNE
  return (unsigned short)(r >> 16);
}

static __device__ __forceinline__ float sigf(float x) {
  return 1.f / (1.f + __expf(-x));
}
static __device__ __forceinline__ float tanhfast(float x) {
  return 1.f - 2.f / (__expf(2.f * x) + 1.f);
}

static __device__ __forceinline__ f32x4 ld4(const float* p, size_t off) {
  return *reinterpret_cast<const f32x4*>(p + off);
}

// Convert fp32 weight (ksrc x 6144, row-major) -> bf16 MFMA-tiled layout.
// dst element ((ct*KC + c)*64 + kb*16 + nl)*8 + j  holds  src[k=c*32+kb*8+j][col=ct*16+nl]
__global__ void convert_w(const float* __restrict__ src, unsigned short* __restrict__ dst,
                          int ksrc, int kc_shift) {
  int tid = blockIdx.x * 256 + threadIdx.x;
  int nl = tid & 15;
  int kb = (tid >> 4) & 3;
  int kc_mask = (1 << kc_shift) - 1;
  int c  = (tid >> 6) & kc_mask;
  int ct = tid >> (6 + kc_shift);
  int col = ct * 16 + nl;
  int kbase = c * 32 + kb * 8;
  union { unsigned short u[8]; int4 v; } o;
#pragma unroll
  for (int j = 0; j < 8; ++j) {
    int k = kbase + j;
    float v = (k < ksrc) ? src[(size_t)k * G3 + col] : 0.f;
    o.u[j] = f2bf(v);
  }
  *reinterpret_cast<int4*>(dst + (size_t)tid * 8) = o.v;
}

// X[t][b][e] = bf16(emb[tokens[b][t]][e]), e padded to 128 with zeros.
__global__ void embed_k(const int* __restrict__ tokens, const float* __restrict__ emb,
                        unsigned short* __restrict__ X) {
  int idx = blockIdx.x * 256 + threadIdx.x;
  int e = idx & (EP - 1);
  int b = (idx >> 7) & (BB - 1);
  int t = idx >> 14;
  float v = 0.f;
  if (e < EE) {
    int tok = tokens[b * TT + t];
    v = emb[(size_t)tok * EE + e];
  }
  X[idx] = f2bf(v);
}

// Store one f32x4 acc plane into G[m][unit]: C/D layout col=lane&15, row=kq*4+reg.
static __device__ __forceinline__ void store_plane(
    float* G, const f32x4& a, int tu, int wave, int lane) {
  int col = tu * 16 + (lane & 15);
  int kq = lane >> 4;
#pragma unroll
  for (int r = 0; r < 4; ++r) {
    int m = wave * 16 + kq * 4 + r;
    G[(size_t)m * UU + col] = a[r];
  }
}

// Pipelined step dispatch d (0..80): 768 blocks x 512 threads, 3 blocks/CU.
// block = grp*128 + tu;  grp = g*2 + khalf;  g: 0=L0, 1=L1-input, 2=L1-recurrent.
// Weight tile staged via dwordx4->VGPR->LDS double buffer; each weight byte
// fetched once per block; all 8 waves consume B-fragments from LDS.
// After storing split-K partial planes, a device-scope ticket counter elects
// the LAST arriving contributor block of each 16-unit slice to combine the
// partials, apply bias + gate nonlinearity, and write h directly (no
// separate gates kernel).  L0 slice: 2 contributors; L1 slice: 4.
__global__ __launch_bounds__(512, 6) void step_gemms(
    int d,
    const unsigned short* __restrict__ X,
    const unsigned short* __restrict__ W0K, const unsigned short* __restrict__ W0R,
    const unsigned short* __restrict__ W1K, const unsigned short* __restrict__ W1R,
    unsigned short* H0B, unsigned short* H1B,      // bf16 states (read as A, written by combiner)
    float* H0F, float* H1F,                        // fp32 states
    float* G0, float* G1I, float* G1R,             // partial planes
    const float* __restrict__ b0, const float* __restrict__ b1,
    int* cnt_base) {
  int grp = blockIdx.x >> 7;
  int tu = blockIdx.x & 127;
  int g = grp >> 1;
  int kh = grp & 1;
  int lane = threadIdx.x & 63;
  int wave = threadIdx.x >> 6;
  int nl = lane & 15;
  int kq = lane >> 4;
  int mrow = wave * 16 + nl;

  __shared__ unsigned short sbuf[2][24 * 512];   // 2 x 24 KB weight chunks
  __shared__ int s_tick;

  const unsigned short* A;
  const unsigned short* W;
  if (g == 0)      { if (d >= TT) return; A = H0B; W = W0R; }
  else if (g == 1) { if (d <  1)  return; A = H0B; W = W1K; }
  else             { if (d <  1)  return; A = H1B; W = W1R; }

  f32x4 acc[3]  = {{0,0,0,0},{0,0,0,0},{0,0,0,0}};
  f32x4 acci[3] = {{0,0,0,0},{0,0,0,0},{0,0,0,0}};

  // role0 khalf0: tiny input projection (K=128 padded), direct loads (L2-hot)
  if (g == 0 && kh == 0) {
    const unsigned short* xp = X + (size_t)d * BB * EP + (size_t)mrow * EP + kq * 8;
    const unsigned short* wp = W0K + (size_t)tu * 4 * 512 + (size_t)lane * 8;
#pragma unroll
    for (int c = 0; c < 4; ++c) {
      bf16x8 a = *reinterpret_cast<const bf16x8*>(xp + c * 32);
#pragma unroll
      for (int gg = 0; gg < 3; ++gg) {
        bf16x8 b = *reinterpret_cast<const bf16x8*>(wp + (size_t)gg * (128 * 4 * 512) + (size_t)c * 512);
        acci[gg] = __builtin_amdgcn_mfma_f32_16x16x32_bf16(a, b, acci[gg], 0, 0, 0);
      }
    }
  }

  const int c0 = kh * 32;                      // this block's K-chunk base
  const unsigned short* ap = A + (size_t)mrow * UU + kq * 8;
  const unsigned short* wlane = W + (size_t)tu * 64 * 512 + (size_t)lane * 8;
  const size_t GS = (size_t)128 * 64 * 512;    // gate stride in tiled layout

  // prologue: load chunk 0 rows into regs, write to buf0
  int4 r0, r1, r2;
  {
    const unsigned short* src = wlane + (size_t)(c0 + wave) * 512;
    r0 = *reinterpret_cast<const int4*>(src);
    r1 = *reinterpret_cast<const int4*>(src + GS);
    r2 = *reinterpret_cast<const int4*>(src + 2 * GS);
    *reinterpret_cast<int4*>(&sbuf[0][(wave * 3 + 0) * 512 + lane * 8]) = r0;
    *reinterpret_cast<int4*>(&sbuf[0][(wave * 3 + 1) * 512 + lane * 8]) = r1;
    *reinterpret_cast<int4*>(&sbuf[0][(wave * 3 + 2) * 512 + lane * 8]) = r2;
  }
  __syncthreads();

  for (int it = 0; it < 4; ++it) {
    // issue next chunk's global loads early (deep vmem queue hides latency)
    if (it < 3) {
      const unsigned short* src = wlane + (size_t)(c0 + (it + 1) * 8 + wave) * 512;
      r0 = *reinterpret_cast<const int4*>(src);
      r1 = *reinterpret_cast<const int4*>(src + GS);
      r2 = *reinterpret_cast<const int4*>(src + 2 * GS);
    }
    // compute current chunk from LDS
#pragma unroll
    for (int h = 0; h < 2; ++h) {
      bf16x8 a[4];
#pragma unroll
      for (int j = 0; j < 4; ++j)
        a[j] = *reinterpret_cast<const bf16x8*>(ap + (size_t)(c0 + it * 8 + h * 4 + j) * 32);
#pragma unroll
      for (int j = 0; j < 4; ++j) {
#pragma unroll
        for (int gg = 0; gg < 3; ++gg) {
          bf16x8 b = *reinterpret_cast<const bf16x8*>(
              &sbuf[it & 1][((h * 4 + j) * 3 + gg) * 512 + lane * 8]);
          acc[gg] = __builtin_amdgcn_mfma_f32_16x16x32_bf16(a[j], b, acc[gg], 0, 0, 0);
        }
      }
    }
    // stash next chunk into the other LDS buffer
    if (it < 3) {
      int nb = (it + 1) & 1;
      *reinterpret_cast<int4*>(&sbuf[nb][(wave * 3 + 0) * 512 + lane * 8]) = r0;
      *reinterpret_cast<int4*>(&sbuf[nb][(wave * 3 + 1) * 512 + lane * 8]) = r1;
      *reinterpret_cast<int4*>(&sbuf[nb][(wave * 3 + 2) * 512 + lane * 8]) = r2;
    }
    __syncthreads();
  }

  // write partial planes
  if (g == 0) {
    if (kh == 0) {
      store_plane(G0 + 0 * PLANE, acci[0] + acc[0], tu, wave, lane);  // z partial a (+input)
      store_plane(G0 + 1 * PLANE, acci[1] + acc[1], tu, wave, lane);  // r partial a (+input)
      store_plane(G0 + 2 * PLANE, acci[2], tu, wave, lane);           // ih (full)
      store_plane(G0 + 3 * PLANE, acc[2], tu, wave, lane);            // hh partial a
    } else {
      store_plane(G0 + 4 * PLANE, acc[0], tu, wave, lane);            // z partial b
      store_plane(G0 + 5 * PLANE, acc[1], tu, wave, lane);            // r partial b
      store_plane(G0 + 6 * PLANE, acc[2], tu, wave, lane);            // hh partial b
    }
  } else if (g == 1) {
    store_plane(G1I + (kh * 3 + 0) * PLANE, acc[0], tu, wave, lane);
    store_plane(G1I + (kh * 3 + 1) * PLANE, acc[1], tu, wave, lane);
    store_plane(G1I + (kh * 3 + 2) * PLANE, acc[2], tu, wave, lane);
  } else {
    store_plane(G1R + (kh * 3 + 0) * PLANE, acc[0], tu, wave, lane);
    store_plane(G1R + (kh * 3 + 1) * PLANE, acc[1], tu, wave, lane);
    store_plane(G1R + (kh * 3 + 2) * PLANE, acc[2], tu, wave, lane);
  }

  // ---- ticket: last arriving contributor combines this 16-unit slice ----
  __threadfence();                 // release our plane stores (device scope)
  __syncthreads();                 // all threads' stores issued+fenced
  if (threadIdx.x == 0) {
    int cidx = (g == 0) ? tu : 128 + tu;
    s_tick = __hip_atomic_fetch_add(&cnt_base[cidx], 1, __ATOMIC_ACQ_REL,
                                    __HIP_MEMORY_SCOPE_AGENT);
  }
  __syncthreads();
  int need = (g == 0) ? 2 : 4;
  if (s_tick != need - 1) return;
  __threadfence();                 // acquire partners' plane stores

  // combine: 512 threads x 4 units each cover 128 rows x 16 units
  int t = threadIdx.x;
  int m = t >> 2;                  // batch row 0..127
  int uq = (t & 3) * 4;            // unit quad within slice
  size_t off = (size_t)m * UU + tu * 16 + uq;
  int u = tu * 16 + uq;            // global unit index (quad base)

  if (g == 0) {
    f32x4 zs = ld4(G0 + 0 * PLANE, off) + ld4(G0 + 4 * PLANE, off)
             + ld4(b0, u) + ld4(b0, G3 + u);
    f32x4 rs = ld4(G0 + 1 * PLANE, off) + ld4(G0 + 5 * PLANE, off)
             + ld4(b0, UU + u) + ld4(b0, G3 + UU + u);
    f32x4 ih = ld4(G0 + 2 * PLANE, off) + ld4(b0, 2 * UU + u);
    f32x4 hh = ld4(G0 + 3 * PLANE, off) + ld4(G0 + 6 * PLANE, off)
             + ld4(b0, G3 + 2 * UU + u);
    f32x4 hold = ld4(H0F, off);
    f32x4 hn;
    unsigned int pk[2];
#pragma unroll
    for (int i = 0; i < 4; ++i) {
      float z = sigf(zs[i]), r = sigf(rs[i]);
      float cand = tanhfast(ih[i] + r * hh[i]);
      hn[i] = z * hold[i] + (1.f - z) * cand;
    }
    pk[0] = (unsigned int)f2bf(hn[0]) | ((unsigned int)f2bf(hn[1]) << 16);
    pk[1] = (unsigned int)f2bf(hn[2]) | ((unsigned int)f2bf(hn[3]) << 16);
    *reinterpret_cast<f32x4*>(H0F + off) = hn;
    *reinterpret_cast<uint2*>(H0B + off) = make_uint2(pk[0], pk[1]);
  } else {
    f32x4 iz = ld4(G1I + 0 * PLANE, off) + ld4(G1I + 3 * PLANE, off) + ld4(b1, u);
    f32x4 ir = ld4(G1I + 1 * PLANE, off) + ld4(G1I + 4 * PLANE, off) + ld4(b1, UU + u);
    f32x4 ih = ld4(G1I + 2 * PLANE, off) + ld4(G1I + 5 * PLANE, off) + ld4(b1, 2 * UU + u);
    f32x4 hz = ld4(G1R + 0 * PLANE, off) + ld4(G1R + 3 * PLANE, off) + ld4(b1, G3 + u);
    f32x4 hr = ld4(G1R + 1 * PLANE, off) + ld4(G1R + 4 * PLANE, off) + ld4(b1, G3 + UU + u);
    f32x4 hh = ld4(G1R + 2 * PLANE, off) + ld4(G1R + 5 * PLANE, off) + ld4(b1, G3 + 2 * UU + u);
    f32x4 hold = ld4(H1F, off);
    f32x4 hn;
    unsigned int pk[2];
#pragma unroll
    for (int i = 0; i < 4; ++i) {
      float z = sigf(iz[i] + hz[i]), r = sigf(ir[i] + hr[i]);
      float cand = tanhfast(ih[i] + r * hh[i]);
      hn[i] = z * hold[i] + (1.f - z) * cand;
    }
    pk[0] = (unsigned int)f2bf(hn[0]) | ((unsigned int)f2bf(hn[1]) << 16);
    pk[1] = (unsigned int)f2bf(hn[2]) | ((unsigned int)f2bf(hn[3]) << 16);
    *reinterpret_cast<f32x4*>(H1F + off) = hn;
    *reinterpret_cast<uint2*>(H1B + off) = make_uint2(pk[0], pk[1]);
  }
}

// logits = sigmoid(h1 @ wout + bout): 128 blocks x 64 threads, one row each.
__global__ void out_k(const float* __restrict__ h1, const float* __restrict__ wout,
                      const float* __restrict__ bout, float* __restrict__ out) {
  int row = blockIdx.x;
  int lane = threadIdx.x;
  float s = 0.f;
  for (int i = lane; i < UU; i += 64) s += h1[(size_t)row * UU + i] * wout[i];
#pragma unroll
  for (int off = 32; off > 0; off >>= 1) s += __shfl_down(s, off);
  if (lane == 0) out[row] = 1.f / (1.f + __expf(-(s + bout[0])));
}

extern "C" void kernel_launch(void* const* d_in, const int* in_sizes, int n_in,
                              void* d_out, int out_size, void* d_ws, size_t ws_size,
                              hipStream_t stream) {
  const int*   tokens = (const int*)  d_in[0];
  const float* emb    = (const float*)d_in[1];
  const float* k0     = (const float*)d_in[2];
  const float* r0     = (const float*)d_in[3];
  const float* b0     = (const float*)d_in[4];
  const float* k1     = (const float*)d_in[5];
  const float* r1     = (const float*)d_in[6];
  const float* b1     = (const float*)d_in[7];
  const float* wout   = (const float*)d_in[8];
  const float* bout   = (const float*)d_in[9];
  float* out = (float*)d_out;

  char* ws = (char*)d_ws;
  unsigned short* W0K = (unsigned short*)(ws + 0);          //  1.5 MB
  unsigned short* W0R = (unsigned short*)(ws + 1572864);    // 25.2 MB
  unsigned short* W1K = (unsigned short*)(ws + 26738688);   // 25.2 MB
  unsigned short* W1R = (unsigned short*)(ws + 51904512);   // 25.2 MB
  unsigned short* X   = (unsigned short*)(ws + 77070336);   //  2.6 MB
  float* H0F          = (float*)(ws + 79691776);            //  1 MB fp32 state
  float* H1F          = (float*)(ws + 80740352);            //  1 MB
  unsigned short* H0B = (unsigned short*)(ws + 81788928);   //  0.5 MB bf16 state
  unsigned short* H1B = (unsigned short*)(ws + 82313216);   //  0.5 MB
  int* CNT            = (int*)(ws + 82837504);              //  128 KB ticket counters
  float* G0           = (float*)(ws + 82968576);            //  7 MB (7 planes)
  float* G1I          = (float*)(ws + 90308608);            //  6 MB (6 planes)
  float* G1R          = (float*)(ws + 96600064);            //  6 MB (6 planes)
  // total ws use: 102,891,520 bytes

  // zero h state + ticket counters (contiguous H0F,H1F,H0B,H1B,CNT)
  hipMemsetAsync(ws + 79691776, 0, 3276800, stream);

  // weight conversion to tiled bf16
  convert_w<<<384,  256, 0, stream>>>(k0, W0K, 100,  2);   // KC=4 (K padded to 128)
  convert_w<<<6144, 256, 0, stream>>>(r0, W0R, 2048, 6);   // KC=64
  convert_w<<<6144, 256, 0, stream>>>(k1, W1K, 2048, 6);
  convert_w<<<6144, 256, 0, stream>>>(r1, W1R, 2048, 6);

  // embedding gather (time-major, padded)
  embed_k<<<5120, 256, 0, stream>>>(tokens, emb, X);

  // 81 pipelined fused dispatches: d computes h0(d) and h1(d-1) concurrently
  for (int d = 0; d <= TT; ++d) {
    step_gemms<<<768, 512, 0, stream>>>(d, X, W0K, W0R, W1K, W1R,
                                        H0B, H1B, H0F, H1F,
                                        G0, G1I, G1R, b0, b1,
                                        CNT + d * 256);
  }

  out_k<<<128, 64, 0, stream>>>(H1F, wout, bout, out);
}

// Round 7
// 3236.375 us; speedup vs baseline: 7.1481x; 7.1481x over previous
//
#include <hip/hip_runtime.h>
#include <cstdint>
#include <cstddef>

#define BB 128    // batch
#define TT 80     // seq
#define EE 100    // emb dim
#define EP 128    // padded emb dim
#define UU 2048   // units
#define G3 6144   // 3*UU
#define PLANE (BB * UU)   // 262144 elements, one gate pre-activation plane

typedef __bf16 bf16x8 __attribute__((ext_vector_type(8)));
typedef float f32x4 __attribute__((ext_vector_type(4)));

static __device__ __forceinline__ unsigned short f2bf(float x) {
  union { float f; unsigned int u; } a; a.f = x;
  unsigned int r = a.u + 0x7fffu + ((a.u >> 16) & 1u);  // RNE
  return (unsigned short)(r >> 16);
}

static __device__ __forceinline__ float sigf(float x) {
  return 1.f / (1.f + __expf(-x));
}
static __device__ __forceinline__ float tanhfast(float x) {
  return 1.f - 2.f / (__expf(2.f * x) + 1.f);
}

// Convert fp32 weight (ksrc x 6144, row-major) -> bf16 MFMA-tiled layout.
// dst element ((ct*KC + c)*64 + kb*16 + nl)*8 + j  holds  src[k=c*32+kb*8+j][col=ct*16+nl]
__global__ void convert_w(const float* __restrict__ src, unsigned short* __restrict__ dst,
                          int ksrc, int kc_shift) {
  int tid = blockIdx.x * 256 + threadIdx.x;
  int nl = tid & 15;
  int kb = (tid >> 4) & 3;
  int kc_mask = (1 << kc_shift) - 1;
  int c  = (tid >> 6) & kc_mask;
  int ct = tid >> (6 + kc_shift);
  int col = ct * 16 + nl;
  int kbase = c * 32 + kb * 8;
  union { unsigned short u[8]; int4 v; } o;
#pragma unroll
  for (int j = 0; j < 8; ++j) {
    int k = kbase + j;
    float v = (k < ksrc) ? src[(size_t)k * G3 + col] : 0.f;
    o.u[j] = f2bf(v);
  }
  *reinterpret_cast<int4*>(dst + (size_t)tid * 8) = o.v;
}

// X[t][b][e] = bf16(emb[tokens[b][t]][e]), e padded to 128 with zeros.
__global__ void embed_k(const int* __restrict__ tokens, const float* __restrict__ emb,
                        unsigned short* __restrict__ X) {
  int idx = blockIdx.x * 256 + threadIdx.x;
  int e = idx & (EP - 1);
  int b = (idx >> 7) & (BB - 1);
  int t = idx >> 14;
  float v = 0.f;
  if (e < EE) {
    int tok = tokens[b * TT + t];
    v = emb[(size_t)tok * EE + e];
  }
  X[idx] = f2bf(v);
}

// Store one f32x4 acc plane: C/D layout col=lane&15, row=kq*4+reg; m-tile index mt8.
static __device__ __forceinline__ void store_plane(
    float* __restrict__ G, const f32x4& a, int tu, int mt8, int lane) {
  int col = tu * 16 + (lane & 15);
  int kq = lane >> 4;
#pragma unroll
  for (int r = 0; r < 4; ++r) {
    int m = mt8 * 16 + kq * 4 + r;
    G[(size_t)m * UU + col] = a[r];
  }
}

// Pipelined step dispatch d (0..80): 768 blocks x 256 threads, 3 blocks/CU.
// block = grp*128 + tu;  grp = g*2 + kh;  g: 0=L0, 1=L1-input, 2=L1-recurrent.
// 4 waves: wave = kg*2 + mg.  mg: rows mg*64..+64 (4 m-tiles).  kg: K-half of
// the block's K=1024 range.  Each B fragment staged once to LDS and reused by
// 4 m-tiles per wave (2x read redundancy total).  kg pairs reduce in-block at
// the epilogue, so partial planes / gates_k match the round-5 scheme exactly.
__global__ __launch_bounds__(256, 3) void step_gemms(
    int d,
    const unsigned short* __restrict__ X,
    const unsigned short* __restrict__ W0K, const unsigned short* __restrict__ W0R,
    const unsigned short* __restrict__ W1K, const unsigned short* __restrict__ W1R,
    const unsigned short* __restrict__ H0B, const unsigned short* __restrict__ H1B,
    float* __restrict__ G0, float* __restrict__ G1I, float* __restrict__ G1R) {
  int grp = blockIdx.x >> 7;
  int tu = blockIdx.x & 127;
  int g = grp >> 1;
  int kh = grp & 1;
  int lane = threadIdx.x & 63;
  int wave = threadIdx.x >> 6;   // 0..3
  int mg = wave & 1;             // row group (64 rows)
  int kg = wave >> 1;            // K sub-half (512)
  int nl = lane & 15;
  int kq = lane >> 4;

  __shared__ unsigned short sbuf[2][12288];   // 2 x 24 KB windows

  const unsigned short* A;
  const unsigned short* W;
  if (g == 0)      { if (d >= TT) return; A = H0B; W = W0R; }
  else if (g == 1) { if (d <  1)  return; A = H0B; W = W1K; }
  else             { if (d <  1)  return; A = H1B; W = W1R; }

  f32x4 acc[4][3];
#pragma unroll
  for (int mt = 0; mt < 4; ++mt)
#pragma unroll
    for (int gg = 0; gg < 3; ++gg) acc[mt][gg] = {0, 0, 0, 0};

  // A-panel row pointers (this wave's 4 m-tiles)
  const unsigned short* ap[4];
#pragma unroll
  for (int mt = 0; mt < 4; ++mt)
    ap[mt] = A + (size_t)(mg * 64 + mt * 16 + nl) * UU + kq * 8;

  // L0 input projection (K=128 padded): kg==0 waves, folded into z/r acc;
  // ih (input-only plane) stored immediately.
  if (g == 0 && kh == 0 && kg == 0) {
    const unsigned short* wp = W0K + (size_t)tu * 4 * 512 + (size_t)lane * 8;
#pragma unroll
    for (int mt = 0; mt < 4; ++mt) {
      const unsigned short* xp = X + (size_t)d * BB * EP
                               + (size_t)(mg * 64 + mt * 16 + nl) * EP + kq * 8;
      f32x4 t2 = {0, 0, 0, 0};
#pragma unroll
      for (int c = 0; c < 4; ++c) {
        bf16x8 a = *reinterpret_cast<const bf16x8*>(xp + c * 32);
        bf16x8 b0 = *reinterpret_cast<const bf16x8*>(wp + (size_t)0 * (128 * 4 * 512) + (size_t)c * 512);
        bf16x8 b1 = *reinterpret_cast<const bf16x8*>(wp + (size_t)1 * (128 * 4 * 512) + (size_t)c * 512);
        bf16x8 b2 = *reinterpret_cast<const bf16x8*>(wp + (size_t)2 * (128 * 4 * 512) + (size_t)c * 512);
        acc[mt][0] = __builtin_amdgcn_mfma_f32_16x16x32_bf16(a, b0, acc[mt][0], 0, 0, 0);
        acc[mt][1] = __builtin_amdgcn_mfma_f32_16x16x32_bf16(a, b1, acc[mt][1], 0, 0, 0);
        t2         = __builtin_amdgcn_mfma_f32_16x16x32_bf16(a, b2, t2, 0, 0, 0);
      }
      store_plane(G0 + 2 * PLANE, t2, tu, mg * 4 + mt, lane);  // ih plane
    }
  }

  // staging setup: 6 int4 slots per thread cover one 24 KB window
  const size_t GS = (size_t)128 * 64 * 512;    // gate stride in tiled layout
  const unsigned short* wsrc[6];
  int soff[6];
  {
    int t = threadIdx.x;
#pragma unroll
    for (int i = 0; i < 6; ++i) {
      int ss = i * 256 + t;
      int b = ss >> 6;                 // 0..23 = (kg_s*4 + kc_s)*3 + g_s
      int l16 = ss & 63;
      int kg_s = b / 12, rem = b % 12, kc_s = rem / 3, g_s = rem % 3;
      wsrc[i] = W + (size_t)g_s * GS
              + ((size_t)(tu * 64 + kh * 32 + kg_s * 16 + kc_s) << 9) + l16 * 8;
      soff[i] = ss * 8;
    }
  }

  // prologue: stage window 0
  {
    int4 v[6];
#pragma unroll
    for (int i = 0; i < 6; ++i) v[i] = *reinterpret_cast<const int4*>(wsrc[i]);
#pragma unroll
    for (int i = 0; i < 6; ++i)
      *reinterpret_cast<int4*>(&sbuf[0][soff[i]]) = v[i];
  }
  __syncthreads();

  for (int w = 0; w < 4; ++w) {
    int4 v[6];
    if (w < 3) {    // issue next window's loads early
#pragma unroll
      for (int i = 0; i < 6; ++i)
        v[i] = *reinterpret_cast<const int4*>(wsrc[i] + (w + 1) * 2048);
    }
    // compute current window: 4 kc-chunks of this wave's K range
#pragma unroll
    for (int kc = 0; kc < 4; ++kc) {
      int kcg = kh * 32 + kg * 16 + w * 4 + kc;
      bf16x8 a[4];
#pragma unroll
      for (int mt = 0; mt < 4; ++mt)
        a[mt] = *reinterpret_cast<const bf16x8*>(ap[mt] + (size_t)kcg * 32);
#pragma unroll
      for (int gg = 0; gg < 3; ++gg) {
        bf16x8 b = *reinterpret_cast<const bf16x8*>(
            &sbuf[w & 1][((kg * 4 + kc) * 3 + gg) * 512 + lane * 8]);
#pragma unroll
        for (int mt = 0; mt < 4; ++mt)
          acc[mt][gg] = __builtin_amdgcn_mfma_f32_16x16x32_bf16(a[mt], b, acc[mt][gg], 0, 0, 0);
      }
    }
    if (w < 3) {
#pragma unroll
      for (int i = 0; i < 6; ++i)
        *reinterpret_cast<int4*>(&sbuf[(w + 1) & 1][soff[i]]) = v[i];
    }
    __syncthreads();
  }

  // epilogue: kg1 dumps C to LDS, kg0 reduces and stores planes
  float* sf = reinterpret_cast<float*>(&sbuf[0][0]);
  if (kg == 1) {
#pragma unroll
    for (int mt = 0; mt < 4; ++mt)
#pragma unroll
      for (int gg = 0; gg < 3; ++gg)
        *reinterpret_cast<f32x4*>(
            &sf[(((mg * 4 + mt) * 3 + gg) * 64 + lane) * 4]) = acc[mt][gg];
  }
  __syncthreads();
  if (kg != 0) return;

#pragma unroll
  for (int mt = 0; mt < 4; ++mt)
#pragma unroll
    for (int gg = 0; gg < 3; ++gg)
      acc[mt][gg] += *reinterpret_cast<const f32x4*>(
          &sf[(((mg * 4 + mt) * 3 + gg) * 64 + lane) * 4]);

#pragma unroll
  for (int mt = 0; mt < 4; ++mt) {
    int mt8 = mg * 4 + mt;
    if (g == 0) {
      if (kh == 0) {
        store_plane(G0 + 0 * PLANE, acc[mt][0], tu, mt8, lane);  // z partial a (+input)
        store_plane(G0 + 1 * PLANE, acc[mt][1], tu, mt8, lane);  // r partial a (+input)
        store_plane(G0 + 3 * PLANE, acc[mt][2], tu, mt8, lane);  // hh partial a
      } else {
        store_plane(G0 + 4 * PLANE, acc[mt][0], tu, mt8, lane);  // z partial b
        store_plane(G0 + 5 * PLANE, acc[mt][1], tu, mt8, lane);  // r partial b
        store_plane(G0 + 6 * PLANE, acc[mt][2], tu, mt8, lane);  // hh partial b
      }
    } else if (g == 1) {
      store_plane(G1I + (kh * 3 + 0) * PLANE, acc[mt][0], tu, mt8, lane);
      store_plane(G1I + (kh * 3 + 1) * PLANE, acc[mt][1], tu, mt8, lane);
      store_plane(G1I + (kh * 3 + 2) * PLANE, acc[mt][2], tu, mt8, lane);
    } else {
      store_plane(G1R + (kh * 3 + 0) * PLANE, acc[mt][0], tu, mt8, lane);
      store_plane(G1R + (kh * 3 + 1) * PLANE, acc[mt][1], tu, mt8, lane);
      store_plane(G1R + (kh * 3 + 2) * PLANE, acc[mt][2], tu, mt8, lane);
    }
  }
}

// Gate math + state update for dispatch d: h0(d) [d<80] and h1(d-1) [d>=1].
__global__ __launch_bounds__(256) void gates_k(
    int d,
    const float* __restrict__ G0, const float* __restrict__ G1I, const float* __restrict__ G1R,
    const float* __restrict__ b0, const float* __restrict__ b1,
    float* __restrict__ H0F, unsigned short* __restrict__ H0B,
    float* __restrict__ H1F, unsigned short* __restrict__ H1B) {
  int idx = blockIdx.x * 256 + threadIdx.x;   // (m, u) flattened, m*2048+u
  int u = idx & (UU - 1);
  if (d < TT) {
    float zs = G0[idx] + G0[4 * PLANE + idx]             + b0[u]        + b0[G3 + u];
    float rs = G0[PLANE + idx] + G0[5 * PLANE + idx]     + b0[UU + u]   + b0[G3 + UU + u];
    float ih = G0[2 * PLANE + idx]                       + b0[2 * UU + u];
    float hh = G0[3 * PLANE + idx] + G0[6 * PLANE + idx] + b0[G3 + 2 * UU + u];
    float z = sigf(zs), r = sigf(rs);
    float cand = tanhfast(ih + r * hh);
    float h = z * H0F[idx] + (1.f - z) * cand;
    H0F[idx] = h;
    H0B[idx] = f2bf(h);
  }
  if (d >= 1) {
    float iz = G1I[idx] + G1I[3 * PLANE + idx]             + b1[u];
    float ir = G1I[PLANE + idx] + G1I[4 * PLANE + idx]     + b1[UU + u];
    float ih = G1I[2 * PLANE + idx] + G1I[5 * PLANE + idx] + b1[2 * UU + u];
    float hz = G1R[idx] + G1R[3 * PLANE + idx]             + b1[G3 + u];
    float hr = G1R[PLANE + idx] + G1R[4 * PLANE + idx]     + b1[G3 + UU + u];
    float hh = G1R[2 * PLANE + idx] + G1R[5 * PLANE + idx] + b1[G3 + 2 * UU + u];
    float z = sigf(iz + hz), r = sigf(ir + hr);
    float cand = tanhfast(ih + r * hh);
    float h = z * H1F[idx] + (1.f - z) * cand;
    H1F[idx] = h;
    H1B[idx] = f2bf(h);
  }
}

// logits = sigmoid(h1 @ wout + bout): 128 blocks x 64 threads, one row each.
__global__ void out_k(const float* __restrict__ h1, const float* __restrict__ wout,
                      const float* __restrict__ bout, float* __restrict__ out) {
  int row = blockIdx.x;
  int lane = threadIdx.x;
  float s = 0.f;
  for (int i = lane; i < UU; i += 64) s += h1[(size_t)row * UU + i] * wout[i];
#pragma unroll
  for (int off = 32; off > 0; off >>= 1) s += __shfl_down(s, off);
  if (lane == 0) out[row] = 1.f / (1.f + __expf(-(s + bout[0])));
}

extern "C" void kernel_launch(void* const* d_in, const int* in_sizes, int n_in,
                              void* d_out, int out_size, void* d_ws, size_t ws_size,
                              hipStream_t stream) {
  const int*   tokens = (const int*)  d_in[0];
  const float* emb    = (const float*)d_in[1];
  const float* k0     = (const float*)d_in[2];
  const float* r0     = (const float*)d_in[3];
  const float* b0     = (const float*)d_in[4];
  const float* k1     = (const float*)d_in[5];
  const float* r1     = (const float*)d_in[6];
  const float* b1     = (const float*)d_in[7];
  const float* wout   = (const float*)d_in[8];
  const float* bout   = (const float*)d_in[9];
  float* out = (float*)d_out;

  char* ws = (char*)d_ws;
  unsigned short* W0K = (unsigned short*)(ws + 0);          //  1.5 MB
  unsigned short* W0R = (unsigned short*)(ws + 1572864);    // 25.2 MB
  unsigned short* W1K = (unsigned short*)(ws + 26738688);   // 25.2 MB
  unsigned short* W1R = (unsigned short*)(ws + 51904512);   // 25.2 MB
  unsigned short* X   = (unsigned short*)(ws + 77070336);   //  2.6 MB
  float* H0F          = (float*)(ws + 79691776);            //  1 MB fp32 state
  float* H1F          = (float*)(ws + 80740352);            //  1 MB
  unsigned short* H0B = (unsigned short*)(ws + 81788928);   //  0.5 MB bf16 state
  unsigned short* H1B = (unsigned short*)(ws + 82313216);   //  0.5 MB
  float* G0           = (float*)(ws + 82837504);            //  7 MB (7 planes)
  float* G1I          = (float*)(ws + 90177536);            //  6 MB (6 planes)
  float* G1R          = (float*)(ws + 96468992);            //  6 MB (6 planes)
  // total ws use: 102,760,448 bytes

  // zero h state (H0F, H1F, H0B, H1B are contiguous): 3 MiB
  hipMemsetAsync(ws + 79691776, 0, 3145728, stream);

  // weight conversion to tiled bf16
  convert_w<<<384,  256, 0, stream>>>(k0, W0K, 100,  2);   // KC=4 (K padded to 128)
  convert_w<<<6144, 256, 0, stream>>>(r0, W0R, 2048, 6);   // KC=64
  convert_w<<<6144, 256, 0, stream>>>(k1, W1K, 2048, 6);
  convert_w<<<6144, 256, 0, stream>>>(r1, W1R, 2048, 6);

  // embedding gather (time-major, padded)
  embed_k<<<5120, 256, 0, stream>>>(tokens, emb, X);

  // 81 pipelined step dispatches: d computes h0(d) and h1(d-1) concurrently
  for (int d = 0; d <= TT; ++d) {
    step_gemms<<<768, 256, 0, stream>>>(d, X, W0K, W0R, W1K, W1R, H0B, H1B,
                                        G0, G1I, G1R);
    gates_k<<<1024, 256, 0, stream>>>(d, G0, G1I, G1R, b0, b1,
                                      H0F, H0B, H1F, H1B);
  }

  out_k<<<128, 64, 0, stream>>>(H1F, wout, bout, out);
}

// Round 8
// 2732.296 us; speedup vs baseline: 8.4668x; 1.1845x over previous
//
#include <hip/hip_runtime.h>
#include <cstdint>
#include <cstddef>

#define BB 128    // batch
#define TT 80     // seq
#define EE 100    // emb dim
#define EP 128    // padded emb dim
#define UU 2048   // units
#define G3 6144   // 3*UU
#define PLANE (BB * UU)   // 262144 elements, one gate pre-activation plane

typedef __bf16 bf16x8 __attribute__((ext_vector_type(8)));
typedef float f32x4 __attribute__((ext_vector_type(4)));

static __device__ __forceinline__ unsigned short f2bf(float x) {
  union { float f; unsigned int u; } a; a.f = x;
  unsigned int r = a.u + 0x7fffu + ((a.u >> 16) & 1u);  // RNE
  return (unsigned short)(r >> 16);
}

static __device__ __forceinline__ float sigf(float x) {
  return 1.f / (1.f + __expf(-x));
}
static __device__ __forceinline__ float tanhfast(float x) {
  return 1.f - 2.f / (__expf(2.f * x) + 1.f);
}

// Convert fp32 weight (ksrc x 6144, row-major) -> bf16 MFMA-tiled layout.
// dst element ((ct*KC + c)*64 + kb*16 + nl)*8 + j  holds  src[k=c*32+kb*8+j][col=ct*16+nl]
__global__ void convert_w(const float* __restrict__ src, unsigned short* __restrict__ dst,
                          int ksrc, int kc_shift) {
  int tid = blockIdx.x * 256 + threadIdx.x;
  int nl = tid & 15;
  int kb = (tid >> 4) & 3;
  int kc_mask = (1 << kc_shift) - 1;
  int c  = (tid >> 6) & kc_mask;
  int ct = tid >> (6 + kc_shift);
  int col = ct * 16 + nl;
  int kbase = c * 32 + kb * 8;
  union { unsigned short u[8]; int4 v; } o;
#pragma unroll
  for (int j = 0; j < 8; ++j) {
    int k = kbase + j;
    float v = (k < ksrc) ? src[(size_t)k * G3 + col] : 0.f;
    o.u[j] = f2bf(v);
  }
  *reinterpret_cast<int4*>(dst + (size_t)tid * 8) = o.v;
}

// X[t][b][e] = bf16(emb[tokens[b][t]][e]), e padded to 128 with zeros.
__global__ void embed_k(const int* __restrict__ tokens, const float* __restrict__ emb,
                        unsigned short* __restrict__ X) {
  int idx = blockIdx.x * 256 + threadIdx.x;
  int e = idx & (EP - 1);
  int b = (idx >> 7) & (BB - 1);
  int t = idx >> 14;
  float v = 0.f;
  if (e < EE) {
    int tok = tokens[b * TT + t];
    v = emb[(size_t)tok * EE + e];
  }
  X[idx] = f2bf(v);
}

// Store one f32x4 acc plane: C/D layout col=lane&15, row=kq*4+reg.
static __device__ __forceinline__ void store_plane(
    float* __restrict__ G, const f32x4& a, int ct16, int mt8, int lane) {
  int col = ct16 * 16 + (lane & 15);
  int kq = lane >> 4;
#pragma unroll
  for (int r = 0; r < 4; ++r) {
    int m = mt8 * 16 + kq * 4 + r;
    G[(size_t)m * UU + col] = a[r];
  }
}

// Pipelined step dispatch d (0..80): 768 blocks x 256 threads, 3 blocks/CU.
// blockIdx = g*256 + kh*64 + tu.  g: 0=L0, 1=L1-input, 2=L1-recurrent.
// tu: 32-unit column tile (2 n-tiles) -> halves per-dispatch A(h)-rereads.
// kh: K quarter (512).  4 waves = mg (32 rows, 2 m-tiles each).
// A fragments register-double-buffered and issued BEFORE the W prefetch each
// phase (in-order vmcnt retirement: A waits don't drain the L3-latency W queue).
__global__ __launch_bounds__(256, 3) void step_gemms(
    int d,
    const unsigned short* __restrict__ X,
    const unsigned short* __restrict__ W0K, const unsigned short* __restrict__ W0R,
    const unsigned short* __restrict__ W1K, const unsigned short* __restrict__ W1R,
    const unsigned short* __restrict__ H0B, const unsigned short* __restrict__ H1B,
    float* __restrict__ G0, float* __restrict__ G1I, float* __restrict__ G1R) {
  int tu = blockIdx.x & 63;
  int kh = (blockIdx.x >> 6) & 3;
  int g  = blockIdx.x >> 8;
  int lane = threadIdx.x & 63;
  int wave = threadIdx.x >> 6;   // mg: rows wave*32 .. +32
  int nl = lane & 15;
  int kq = lane >> 4;

  __shared__ unsigned short sbuf[2][12288];   // 2 x 24 KB weight windows

  const unsigned short* A;
  const unsigned short* W;
  if (g == 0)      { if (d >= TT) return; A = H0B; W = W0R; }
  else if (g == 1) { if (d <  1)  return; A = H0B; W = W1K; }
  else             { if (d <  1)  return; A = H1B; W = W1R; }

  f32x4 acc[2][2][3];   // [mt][nt][gate]
#pragma unroll
  for (int mt = 0; mt < 2; ++mt)
#pragma unroll
    for (int nt = 0; nt < 2; ++nt)
#pragma unroll
      for (int gg = 0; gg < 3; ++gg) acc[mt][nt][gg] = {0, 0, 0, 0};

  const unsigned short* ap[2];
#pragma unroll
  for (int mt = 0; mt < 2; ++mt)
    ap[mt] = A + (size_t)(wave * 32 + mt * 16 + nl) * UU + kq * 8;

  // L0 input projection (K=128 padded), kh==0 blocks only.
  if (g == 0 && kh == 0) {
#pragma unroll
    for (int nt = 0; nt < 2; ++nt) {
      const unsigned short* wp = W0K + (size_t)(tu * 2 + nt) * 4 * 512 + (size_t)lane * 8;
#pragma unroll
      for (int mt = 0; mt < 2; ++mt) {
        const unsigned short* xp = X + (size_t)d * BB * EP
                                 + (size_t)(wave * 32 + mt * 16 + nl) * EP + kq * 8;
        f32x4 t2 = {0, 0, 0, 0};
#pragma unroll
        for (int c = 0; c < 4; ++c) {
          bf16x8 a  = *reinterpret_cast<const bf16x8*>(xp + c * 32);
          bf16x8 b0 = *reinterpret_cast<const bf16x8*>(wp + (size_t)0 * (128 * 4 * 512) + c * 512);
          bf16x8 b1 = *reinterpret_cast<const bf16x8*>(wp + (size_t)1 * (128 * 4 * 512) + c * 512);
          bf16x8 b2 = *reinterpret_cast<const bf16x8*>(wp + (size_t)2 * (128 * 4 * 512) + c * 512);
          acc[mt][nt][0] = __builtin_amdgcn_mfma_f32_16x16x32_bf16(a, b0, acc[mt][nt][0], 0, 0, 0);
          acc[mt][nt][1] = __builtin_amdgcn_mfma_f32_16x16x32_bf16(a, b1, acc[mt][nt][1], 0, 0, 0);
          t2             = __builtin_amdgcn_mfma_f32_16x16x32_bf16(a, b2, t2, 0, 0, 0);
        }
        store_plane(G0 + 12 * PLANE, t2, tu * 2 + nt, wave * 2 + mt, lane);
      }
    }
  }

  // staging map: 6 int4 per thread cover one 24 KB window
  // slot = (kcw*2 + nt)*3 + gg ;  window advance = 4 kc = 2048 shorts
  const size_t GS = (size_t)128 * 64 * 512;
  int woff[6];
  int soff0 = threadIdx.x * 8;
  {
    int t = threadIdx.x;
#pragma unroll
    for (int i = 0; i < 6; ++i) {
      int ss = i * 256 + t;
      int slot = ss >> 6, l16 = ss & 63;
      int gg = slot % 3, q = slot / 3;
      int nt = q & 1, kcw = q >> 1;
      woff[i] = (int)((size_t)gg * GS + ((size_t)((tu * 2 + nt) * 64 + kh * 16 + kcw) << 9)) + l16 * 8;
    }
  }

  bf16x8 areg[4][2];
  // prologue: A window 0 (issued first), then W window 0
#pragma unroll
  for (int kcw = 0; kcw < 4; ++kcw)
#pragma unroll
    for (int mt = 0; mt < 2; ++mt)
      areg[kcw][mt] = *reinterpret_cast<const bf16x8*>(ap[mt] + (size_t)(kh * 16 + kcw) * 32);
  {
    int4 v[6];
#pragma unroll
    for (int i = 0; i < 6; ++i) v[i] = *reinterpret_cast<const int4*>(W + (size_t)woff[i]);
#pragma unroll
    for (int i = 0; i < 6; ++i)
      *reinterpret_cast<int4*>(&sbuf[0][soff0 + i * 2048]) = v[i];
  }
  __syncthreads();

#pragma unroll
  for (int w = 0; w < 4; ++w) {
    bf16x8 anext[4][2];
    int4 v[6];
    if (w < 3) {
#pragma unroll
      for (int kcw = 0; kcw < 4; ++kcw)
#pragma unroll
        for (int mt = 0; mt < 2; ++mt)
          anext[kcw][mt] = *reinterpret_cast<const bf16x8*>(
              ap[mt] + (size_t)(kh * 16 + (w + 1) * 4 + kcw) * 32);
#pragma unroll
      for (int i = 0; i < 6; ++i)
        v[i] = *reinterpret_cast<const int4*>(W + (size_t)woff[i] + (size_t)(w + 1) * 2048);
    }
#pragma unroll
    for (int kcw = 0; kcw < 4; ++kcw) {
#pragma unroll
      for (int nt = 0; nt < 2; ++nt) {
#pragma unroll
        for (int gg = 0; gg < 3; ++gg) {
          bf16x8 b = *reinterpret_cast<const bf16x8*>(
              &sbuf[w & 1][((kcw * 2 + nt) * 3 + gg) * 512 + lane * 8]);
#pragma unroll
          for (int mt = 0; mt < 2; ++mt)
            acc[mt][nt][gg] = __builtin_amdgcn_mfma_f32_16x16x32_bf16(
                areg[kcw][mt], b, acc[mt][nt][gg], 0, 0, 0);
        }
      }
    }
    if (w < 3) {
      int nb = (w + 1) & 1;
#pragma unroll
      for (int i = 0; i < 6; ++i)
        *reinterpret_cast<int4*>(&sbuf[nb][soff0 + i * 2048]) = v[i];
#pragma unroll
      for (int kcw = 0; kcw < 4; ++kcw)
#pragma unroll
        for (int mt = 0; mt < 2; ++mt) areg[kcw][mt] = anext[kcw][mt];
      __syncthreads();
    }
  }

  // epilogue: partial planes (plane = gate*4 + kh; L0 ih at 12)
#pragma unroll
  for (int mt = 0; mt < 2; ++mt) {
#pragma unroll
    for (int nt = 0; nt < 2; ++nt) {
      int ct16 = tu * 2 + nt;
      int mt8 = wave * 2 + mt;
      float* base = (g == 0) ? G0 : (g == 1) ? G1I : G1R;
      store_plane(base + (0 + kh) * PLANE, acc[mt][nt][0], ct16, mt8, lane);
      store_plane(base + (4 + kh) * PLANE, acc[mt][nt][1], ct16, mt8, lane);
      store_plane(base + (8 + kh) * PLANE, acc[mt][nt][2], ct16, mt8, lane);
    }
  }
}

// Gate math + state update for dispatch d: h0(d) [d<80] and h1(d-1) [d>=1].
__global__ __launch_bounds__(256) void gates_k(
    int d,
    const float* __restrict__ G0, const float* __restrict__ G1I, const float* __restrict__ G1R,
    const float* __restrict__ b0, const float* __restrict__ b1,
    float* __restrict__ H0F, unsigned short* __restrict__ H0B,
    float* __restrict__ H1F, unsigned short* __restrict__ H1B) {
  int idx = blockIdx.x * 256 + threadIdx.x;
  int u = idx & (UU - 1);
  if (d < TT) {
    float zs = G0[idx] + G0[PLANE + idx] + G0[2 * PLANE + idx] + G0[3 * PLANE + idx]
             + b0[u] + b0[G3 + u];
    float rs = G0[4 * PLANE + idx] + G0[5 * PLANE + idx] + G0[6 * PLANE + idx]
             + G0[7 * PLANE + idx] + b0[UU + u] + b0[G3 + UU + u];
    float hh = G0[8 * PLANE + idx] + G0[9 * PLANE + idx] + G0[10 * PLANE + idx]
             + G0[11 * PLANE + idx] + b0[G3 + 2 * UU + u];
    float ih = G0[12 * PLANE + idx] + b0[2 * UU + u];
    float z = sigf(zs), r = sigf(rs);
    float cand = tanhfast(ih + r * hh);
    float h = z * H0F[idx] + (1.f - z) * cand;
    H0F[idx] = h;
    H0B[idx] = f2bf(h);
  }
  if (d >= 1) {
    float iz = G1I[idx] + G1I[PLANE + idx] + G1I[2 * PLANE + idx] + G1I[3 * PLANE + idx] + b1[u];
    float ir = G1I[4 * PLANE + idx] + G1I[5 * PLANE + idx] + G1I[6 * PLANE + idx]
             + G1I[7 * PLANE + idx] + b1[UU + u];
    float ih = G1I[8 * PLANE + idx] + G1I[9 * PLANE + idx] + G1I[10 * PLANE + idx]
             + G1I[11 * PLANE + idx] + b1[2 * UU + u];
    float hz = G1R[idx] + G1R[PLANE + idx] + G1R[2 * PLANE + idx] + G1R[3 * PLANE + idx] + b1[G3 + u];
    float hr = G1R[4 * PLANE + idx] + G1R[5 * PLANE + idx] + G1R[6 * PLANE + idx]
             + G1R[7 * PLANE + idx] + b1[G3 + UU + u];
    float hh = G1R[8 * PLANE + idx] + G1R[9 * PLANE + idx] + G1R[10 * PLANE + idx]
             + G1R[11 * PLANE + idx] + b1[G3 + 2 * UU + u];
    float z = sigf(iz + hz), r = sigf(ir + hr);
    float cand = tanhfast(ih + r * hh);
    float h = z * H1F[idx] + (1.f - z) * cand;
    H1F[idx] = h;
    H1B[idx] = f2bf(h);
  }
}

// logits = sigmoid(h1 @ wout + bout): 128 blocks x 64 threads, one row each.
__global__ void out_k(const float* __restrict__ h1, const float* __restrict__ wout,
                      const float* __restrict__ bout, float* __restrict__ out) {
  int row = blockIdx.x;
  int lane = threadIdx.x;
  float s = 0.f;
  for (int i = lane; i < UU; i += 64) s += h1[(size_t)row * UU + i] * wout[i];
#pragma unroll
  for (int off = 32; off > 0; off >>= 1) s += __shfl_down(s, off);
  if (lane == 0) out[row] = 1.f / (1.f + __expf(-(s + bout[0])));
}

extern "C" void kernel_launch(void* const* d_in, const int* in_sizes, int n_in,
                              void* d_out, int out_size, void* d_ws, size_t ws_size,
                              hipStream_t stream) {
  const int*   tokens = (const int*)  d_in[0];
  const float* emb    = (const float*)d_in[1];
  const float* k0     = (const float*)d_in[2];
  const float* r0     = (const float*)d_in[3];
  const float* b0     = (const float*)d_in[4];
  const float* k1     = (const float*)d_in[5];
  const float* r1     = (const float*)d_in[6];
  const float* b1     = (const float*)d_in[7];
  const float* wout   = (const float*)d_in[8];
  const float* bout   = (const float*)d_in[9];
  float* out = (float*)d_out;

  char* ws = (char*)d_ws;
  unsigned short* W0K = (unsigned short*)(ws + 0);          //  1.5 MB
  unsigned short* W0R = (unsigned short*)(ws + 1572864);    // 25.2 MB
  unsigned short* W1K = (unsigned short*)(ws + 26738688);   // 25.2 MB
  unsigned short* W1R = (unsigned short*)(ws + 51904512);   // 25.2 MB
  unsigned short* X   = (unsigned short*)(ws + 77070336);   //  2.6 MB
  float* H0F          = (float*)(ws + 79691776);            //  1 MB fp32 state
  float* H1F          = (float*)(ws + 80740352);            //  1 MB
  unsigned short* H0B = (unsigned short*)(ws + 81788928);   //  0.5 MB bf16 state
  unsigned short* H1B = (unsigned short*)(ws + 82313216);   //  0.5 MB
  float* G0           = (float*)(ws + 82837504);            // 13 planes (13.6 MB)
  float* G1I          = (float*)(ws + 96468992);            // 12 planes (12.6 MB)
  float* G1R          = (float*)(ws + 109051904);           // 12 planes (12.6 MB)
  // total ws use: 121,634,816 bytes

  // zero h state (H0F, H1F, H0B, H1B are contiguous): 3 MiB
  hipMemsetAsync(ws + 79691776, 0, 3145728, stream);

  // weight conversion to tiled bf16
  convert_w<<<384,  256, 0, stream>>>(k0, W0K, 100,  2);   // KC=4 (K padded to 128)
  convert_w<<<6144, 256, 0, stream>>>(r0, W0R, 2048, 6);   // KC=64
  convert_w<<<6144, 256, 0, stream>>>(k1, W1K, 2048, 6);
  convert_w<<<6144, 256, 0, stream>>>(r1, W1R, 2048, 6);

  // embedding gather (time-major, padded)
  embed_k<<<5120, 256, 0, stream>>>(tokens, emb, X);

  // 81 pipelined step dispatches: d computes h0(d) and h1(d-1) concurrently
  for (int d = 0; d <= TT; ++d) {
    step_gemms<<<768, 256, 0, stream>>>(d, X, W0K, W0R, W1K, W1R, H0B, H1B,
                                        G0, G1I, G1R);
    gates_k<<<1024, 256, 0, stream>>>(d, G0, G1I, G1R, b0, b1,
                                      H0F, H0B, H1F, H1B);
  }

  out_k<<<128, 64, 0, stream>>>(H1F, wout, bout, out);
}

// Round 9
// 2712.747 us; speedup vs baseline: 8.5278x; 1.0072x over previous
//
#include <hip/hip_runtime.h>
#include <cstdint>
#include <cstddef>

#define BB 128    // batch
#define TT 80     // seq
#define EE 100    // emb dim
#define EP 128    // padded emb dim
#define UU 2048   // units
#define G3 6144   // 3*UU
#define PLANE (BB * UU)   // 262144 elements, one gate pre-activation plane

typedef __bf16 bf16x8 __attribute__((ext_vector_type(8)));
typedef float f32x4 __attribute__((ext_vector_type(4)));

static __device__ __forceinline__ unsigned short f2bf(float x) {
  union { float f; unsigned int u; } a; a.f = x;
  unsigned int r = a.u + 0x7fffu + ((a.u >> 16) & 1u);  // RNE
  return (unsigned short)(r >> 16);
}

static __device__ __forceinline__ float sigf(float x) {
  return 1.f / (1.f + __expf(-x));
}
static __device__ __forceinline__ float tanhfast(float x) {
  return 1.f - 2.f / (__expf(2.f * x) + 1.f);
}

// accumulate 8 bf16 plane values (one int4 load) into float[8]
static __device__ __forceinline__ void acc8(float* s, const unsigned short* p) {
  int4 v = *reinterpret_cast<const int4*>(p);
  unsigned int w0 = (unsigned int)v.x, w1 = (unsigned int)v.y,
               w2 = (unsigned int)v.z, w3 = (unsigned int)v.w;
  union { unsigned int u; float f; } c;
  c.u = w0 << 16;         s[0] += c.f;
  c.u = w0 & 0xffff0000u; s[1] += c.f;
  c.u = w1 << 16;         s[2] += c.f;
  c.u = w1 & 0xffff0000u; s[3] += c.f;
  c.u = w2 << 16;         s[4] += c.f;
  c.u = w2 & 0xffff0000u; s[5] += c.f;
  c.u = w3 << 16;         s[6] += c.f;
  c.u = w3 & 0xffff0000u; s[7] += c.f;
}

static __device__ __forceinline__ void addbias8(float* s, const float* b) {
  f32x4 x0 = *reinterpret_cast<const f32x4*>(b);
  f32x4 x1 = *reinterpret_cast<const f32x4*>(b + 4);
#pragma unroll
  for (int i = 0; i < 4; ++i) { s[i] += x0[i]; s[4 + i] += x1[i]; }
}

// Convert fp32 weight (ksrc x 6144, row-major) -> bf16 MFMA-tiled layout.
// dst element ((ct*KC + c)*64 + kb*16 + nl)*8 + j  holds  src[k=c*32+kb*8+j][col=ct*16+nl]
__global__ void convert_w(const float* __restrict__ src, unsigned short* __restrict__ dst,
                          int ksrc, int kc_shift) {
  int tid = blockIdx.x * 256 + threadIdx.x;
  int nl = tid & 15;
  int kb = (tid >> 4) & 3;
  int kc_mask = (1 << kc_shift) - 1;
  int c  = (tid >> 6) & kc_mask;
  int ct = tid >> (6 + kc_shift);
  int col = ct * 16 + nl;
  int kbase = c * 32 + kb * 8;
  union { unsigned short u[8]; int4 v; } o;
#pragma unroll
  for (int j = 0; j < 8; ++j) {
    int k = kbase + j;
    float v = (k < ksrc) ? src[(size_t)k * G3 + col] : 0.f;
    o.u[j] = f2bf(v);
  }
  *reinterpret_cast<int4*>(dst + (size_t)tid * 8) = o.v;
}

// X[t][b][e] = bf16(emb[tokens[b][t]][e]), e padded to 128 with zeros.
__global__ void embed_k(const int* __restrict__ tokens, const float* __restrict__ emb,
                        unsigned short* __restrict__ X) {
  int idx = blockIdx.x * 256 + threadIdx.x;
  int e = idx & (EP - 1);
  int b = (idx >> 7) & (BB - 1);
  int t = idx >> 14;
  float v = 0.f;
  if (e < EE) {
    int tok = tokens[b * TT + t];
    v = emb[(size_t)tok * EE + e];
  }
  X[idx] = f2bf(v);
}

// Store one f32x4 acc plane as bf16: C/D layout col=lane&15, row=kq*4+reg.
static __device__ __forceinline__ void store_plane(
    unsigned short* __restrict__ G, const f32x4& a, int ct16, int mt8, int lane) {
  int col = ct16 * 16 + (lane & 15);
  int kq = lane >> 4;
#pragma unroll
  for (int r = 0; r < 4; ++r) {
    int m = mt8 * 16 + kq * 4 + r;
    G[(size_t)m * UU + col] = f2bf(a[r]);
  }
}

// Pipelined step dispatch d (0..80): 768 blocks x 256 threads, 3 blocks/CU.
// blockIdx = g*256 + kh*64 + tu.  g: 0=L0, 1=L1-input, 2=L1-recurrent.
// tu: 32-unit column tile (2 n-tiles).  kh: K quarter (512).  4 waves = mg.
// A fragments register-double-buffered and issued BEFORE the W prefetch each
// phase.  Partial planes stored as bf16 (halves plane traffic both ways).
__global__ __launch_bounds__(256, 3) void step_gemms(
    int d,
    const unsigned short* __restrict__ X,
    const unsigned short* __restrict__ W0K, const unsigned short* __restrict__ W0R,
    const unsigned short* __restrict__ W1K, const unsigned short* __restrict__ W1R,
    const unsigned short* __restrict__ H0B, const unsigned short* __restrict__ H1B,
    unsigned short* __restrict__ G0, unsigned short* __restrict__ G1I,
    unsigned short* __restrict__ G1R) {
  int tu = blockIdx.x & 63;
  int kh = (blockIdx.x >> 6) & 3;
  int g  = blockIdx.x >> 8;
  int lane = threadIdx.x & 63;
  int wave = threadIdx.x >> 6;   // mg: rows wave*32 .. +32
  int nl = lane & 15;
  int kq = lane >> 4;

  __shared__ unsigned short sbuf[2][12288];   // 2 x 24 KB weight windows

  const unsigned short* A;
  const unsigned short* W;
  if (g == 0)      { if (d >= TT) return; A = H0B; W = W0R; }
  else if (g == 1) { if (d <  1)  return; A = H0B; W = W1K; }
  else             { if (d <  1)  return; A = H1B; W = W1R; }

  f32x4 acc[2][2][3];   // [mt][nt][gate]
#pragma unroll
  for (int mt = 0; mt < 2; ++mt)
#pragma unroll
    for (int nt = 0; nt < 2; ++nt)
#pragma unroll
      for (int gg = 0; gg < 3; ++gg) acc[mt][nt][gg] = {0, 0, 0, 0};

  const unsigned short* ap[2];
#pragma unroll
  for (int mt = 0; mt < 2; ++mt)
    ap[mt] = A + (size_t)(wave * 32 + mt * 16 + nl) * UU + kq * 8;

  // L0 input projection (K=128 padded), kh==0 blocks only.
  if (g == 0 && kh == 0) {
#pragma unroll
    for (int nt = 0; nt < 2; ++nt) {
      const unsigned short* wp = W0K + (size_t)(tu * 2 + nt) * 4 * 512 + (size_t)lane * 8;
#pragma unroll
      for (int mt = 0; mt < 2; ++mt) {
        const unsigned short* xp = X + (size_t)d * BB * EP
                                 + (size_t)(wave * 32 + mt * 16 + nl) * EP + kq * 8;
        f32x4 t2 = {0, 0, 0, 0};
#pragma unroll
        for (int c = 0; c < 4; ++c) {
          bf16x8 a  = *reinterpret_cast<const bf16x8*>(xp + c * 32);
          bf16x8 b0 = *reinterpret_cast<const bf16x8*>(wp + (size_t)0 * (128 * 4 * 512) + c * 512);
          bf16x8 b1 = *reinterpret_cast<const bf16x8*>(wp + (size_t)1 * (128 * 4 * 512) + c * 512);
          bf16x8 b2 = *reinterpret_cast<const bf16x8*>(wp + (size_t)2 * (128 * 4 * 512) + c * 512);
          acc[mt][nt][0] = __builtin_amdgcn_mfma_f32_16x16x32_bf16(a, b0, acc[mt][nt][0], 0, 0, 0);
          acc[mt][nt][1] = __builtin_amdgcn_mfma_f32_16x16x32_bf16(a, b1, acc[mt][nt][1], 0, 0, 0);
          t2             = __builtin_amdgcn_mfma_f32_16x16x32_bf16(a, b2, t2, 0, 0, 0);
        }
        store_plane(G0 + (size_t)12 * PLANE, t2, tu * 2 + nt, wave * 2 + mt, lane);
      }
    }
  }

  // staging map: 6 int4 per thread cover one 24 KB window
  const size_t GS = (size_t)128 * 64 * 512;
  int woff[6];
  int soff0 = threadIdx.x * 8;
  {
    int t = threadIdx.x;
#pragma unroll
    for (int i = 0; i < 6; ++i) {
      int ss = i * 256 + t;
      int slot = ss >> 6, l16 = ss & 63;
      int gg = slot % 3, q = slot / 3;
      int nt = q & 1, kcw = q >> 1;
      woff[i] = (int)((size_t)gg * GS + ((size_t)((tu * 2 + nt) * 64 + kh * 16 + kcw) << 9)) + l16 * 8;
    }
  }

  bf16x8 areg[4][2];
#pragma unroll
  for (int kcw = 0; kcw < 4; ++kcw)
#pragma unroll
    for (int mt = 0; mt < 2; ++mt)
      areg[kcw][mt] = *reinterpret_cast<const bf16x8*>(ap[mt] + (size_t)(kh * 16 + kcw) * 32);
  {
    int4 v[6];
#pragma unroll
    for (int i = 0; i < 6; ++i) v[i] = *reinterpret_cast<const int4*>(W + (size_t)woff[i]);
#pragma unroll
    for (int i = 0; i < 6; ++i)
      *reinterpret_cast<int4*>(&sbuf[0][soff0 + i * 2048]) = v[i];
  }
  __syncthreads();

#pragma unroll
  for (int w = 0; w < 4; ++w) {
    bf16x8 anext[4][2];
    int4 v[6];
    if (w < 3) {
#pragma unroll
      for (int kcw = 0; kcw < 4; ++kcw)
#pragma unroll
        for (int mt = 0; mt < 2; ++mt)
          anext[kcw][mt] = *reinterpret_cast<const bf16x8*>(
              ap[mt] + (size_t)(kh * 16 + (w + 1) * 4 + kcw) * 32);
#pragma unroll
      for (int i = 0; i < 6; ++i)
        v[i] = *reinterpret_cast<const int4*>(W + (size_t)woff[i] + (size_t)(w + 1) * 2048);
    }
#pragma unroll
    for (int kcw = 0; kcw < 4; ++kcw) {
#pragma unroll
      for (int nt = 0; nt < 2; ++nt) {
#pragma unroll
        for (int gg = 0; gg < 3; ++gg) {
          bf16x8 b = *reinterpret_cast<const bf16x8*>(
              &sbuf[w & 1][((kcw * 2 + nt) * 3 + gg) * 512 + lane * 8]);
#pragma unroll
          for (int mt = 0; mt < 2; ++mt)
            acc[mt][nt][gg] = __builtin_amdgcn_mfma_f32_16x16x32_bf16(
                areg[kcw][mt], b, acc[mt][nt][gg], 0, 0, 0);
        }
      }
    }
    if (w < 3) {
      int nb = (w + 1) & 1;
#pragma unroll
      for (int i = 0; i < 6; ++i)
        *reinterpret_cast<int4*>(&sbuf[nb][soff0 + i * 2048]) = v[i];
#pragma unroll
      for (int kcw = 0; kcw < 4; ++kcw)
#pragma unroll
        for (int mt = 0; mt < 2; ++mt) areg[kcw][mt] = anext[kcw][mt];
      __syncthreads();
    }
  }

  // epilogue: bf16 partial planes (plane = gate*4 + kh; L0 ih at 12)
#pragma unroll
  for (int mt = 0; mt < 2; ++mt) {
#pragma unroll
    for (int nt = 0; nt < 2; ++nt) {
      int ct16 = tu * 2 + nt;
      int mt8 = wave * 2 + mt;
      unsigned short* base = (g == 0) ? G0 : (g == 1) ? G1I : G1R;
      store_plane(base + (size_t)(0 + kh) * PLANE, acc[mt][nt][0], ct16, mt8, lane);
      store_plane(base + (size_t)(4 + kh) * PLANE, acc[mt][nt][1], ct16, mt8, lane);
      store_plane(base + (size_t)(8 + kh) * PLANE, acc[mt][nt][2], ct16, mt8, lane);
    }
  }
}

// Gate math + state update for dispatch d: h0(d) [d<80] and h1(d-1) [d>=1].
// 256 blocks x 128 threads; each thread handles 8 consecutive units (int4
// loads of bf16 planes).
__global__ __launch_bounds__(128) void gates_k(
    int d,
    const unsigned short* __restrict__ G0, const unsigned short* __restrict__ G1I,
    const unsigned short* __restrict__ G1R,
    const float* __restrict__ b0, const float* __restrict__ b1,
    float* __restrict__ H0F, unsigned short* __restrict__ H0B,
    float* __restrict__ H1F, unsigned short* __restrict__ H1B) {
  int t = blockIdx.x * 128 + threadIdx.x;   // 32768 threads
  size_t idx = (size_t)t * 8;               // element base (m*2048+u), u multiple of 8
  int u = (int)(idx & (UU - 1));

  if (d < TT) {
    float zs[8] = {0,0,0,0,0,0,0,0}, rs[8] = {0,0,0,0,0,0,0,0};
    float hh[8] = {0,0,0,0,0,0,0,0}, ih[8] = {0,0,0,0,0,0,0,0};
#pragma unroll
    for (int p = 0; p < 4; ++p) {
      acc8(zs, G0 + (size_t)p * PLANE + idx);
      acc8(rs, G0 + (size_t)(4 + p) * PLANE + idx);
      acc8(hh, G0 + (size_t)(8 + p) * PLANE + idx);
    }
    acc8(ih, G0 + (size_t)12 * PLANE + idx);
    addbias8(zs, b0 + u);          addbias8(zs, b0 + G3 + u);
    addbias8(rs, b0 + UU + u);     addbias8(rs, b0 + G3 + UU + u);
    addbias8(ih, b0 + 2 * UU + u);
    addbias8(hh, b0 + G3 + 2 * UU + u);
    f32x4 h0 = *reinterpret_cast<const f32x4*>(H0F + idx);
    f32x4 h1 = *reinterpret_cast<const f32x4*>(H0F + idx + 4);
    float hold[8] = {h0[0], h0[1], h0[2], h0[3], h1[0], h1[1], h1[2], h1[3]};
    float hn[8];
    unsigned int pk[4];
#pragma unroll
    for (int i = 0; i < 8; ++i) {
      float z = sigf(zs[i]), r = sigf(rs[i]);
      float cand = tanhfast(ih[i] + r * hh[i]);
      hn[i] = z * hold[i] + (1.f - z) * cand;
    }
#pragma unroll
    for (int i = 0; i < 4; ++i)
      pk[i] = (unsigned int)f2bf(hn[2 * i]) | ((unsigned int)f2bf(hn[2 * i + 1]) << 16);
    *reinterpret_cast<f32x4*>(H0F + idx)     = f32x4{hn[0], hn[1], hn[2], hn[3]};
    *reinterpret_cast<f32x4*>(H0F + idx + 4) = f32x4{hn[4], hn[5], hn[6], hn[7]};
    *reinterpret_cast<int4*>(H0B + idx) = make_int4(pk[0], pk[1], pk[2], pk[3]);
  }
  if (d >= 1) {
    float iz[8] = {0,0,0,0,0,0,0,0}, ir[8] = {0,0,0,0,0,0,0,0}, ih[8] = {0,0,0,0,0,0,0,0};
    float hz[8] = {0,0,0,0,0,0,0,0}, hr[8] = {0,0,0,0,0,0,0,0}, hh[8] = {0,0,0,0,0,0,0,0};
#pragma unroll
    for (int p = 0; p < 4; ++p) {
      acc8(iz, G1I + (size_t)p * PLANE + idx);
      acc8(ir, G1I + (size_t)(4 + p) * PLANE + idx);
      acc8(ih, G1I + (size_t)(8 + p) * PLANE + idx);
      acc8(hz, G1R + (size_t)p * PLANE + idx);
      acc8(hr, G1R + (size_t)(4 + p) * PLANE + idx);
      acc8(hh, G1R + (size_t)(8 + p) * PLANE + idx);
    }
    addbias8(iz, b1 + u);           addbias8(hz, b1 + G3 + u);
    addbias8(ir, b1 + UU + u);      addbias8(hr, b1 + G3 + UU + u);
    addbias8(ih, b1 + 2 * UU + u);  addbias8(hh, b1 + G3 + 2 * UU + u);
    f32x4 h0 = *reinterpret_cast<const f32x4*>(H1F + idx);
    f32x4 h1 = *reinterpret_cast<const f32x4*>(H1F + idx + 4);
    float hold[8] = {h0[0], h0[1], h0[2], h0[3], h1[0], h1[1], h1[2], h1[3]};
    float hn[8];
    unsigned int pk[4];
#pragma unroll
    for (int i = 0; i < 8; ++i) {
      float z = sigf(iz[i] + hz[i]), r = sigf(ir[i] + hr[i]);
      float cand = tanhfast(ih[i] + r * hh[i]);
      hn[i] = z * hold[i] + (1.f - z) * cand;
    }
#pragma unroll
    for (int i = 0; i < 4; ++i)
      pk[i] = (unsigned int)f2bf(hn[2 * i]) | ((unsigned int)f2bf(hn[2 * i + 1]) << 16);
    *reinterpret_cast<f32x4*>(H1F + idx)     = f32x4{hn[0], hn[1], hn[2], hn[3]};
    *reinterpret_cast<f32x4*>(H1F + idx + 4) = f32x4{hn[4], hn[5], hn[6], hn[7]};
    *reinterpret_cast<int4*>(H1B + idx) = make_int4(pk[0], pk[1], pk[2], pk[3]);
  }
}

// logits = sigmoid(h1 @ wout + bout): 128 blocks x 64 threads, one row each.
__global__ void out_k(const float* __restrict__ h1, const float* __restrict__ wout,
                      const float* __restrict__ bout, float* __restrict__ out) {
  int row = blockIdx.x;
  int lane = threadIdx.x;
  float s = 0.f;
  for (int i = lane; i < UU; i += 64) s += h1[(size_t)row * UU + i] * wout[i];
#pragma unroll
  for (int off = 32; off > 0; off >>= 1) s += __shfl_down(s, off);
  if (lane == 0) out[row] = 1.f / (1.f + __expf(-(s + bout[0])));
}

extern "C" void kernel_launch(void* const* d_in, const int* in_sizes, int n_in,
                              void* d_out, int out_size, void* d_ws, size_t ws_size,
                              hipStream_t stream) {
  const int*   tokens = (const int*)  d_in[0];
  const float* emb    = (const float*)d_in[1];
  const float* k0     = (const float*)d_in[2];
  const float* r0     = (const float*)d_in[3];
  const float* b0     = (const float*)d_in[4];
  const float* k1     = (const float*)d_in[5];
  const float* r1     = (const float*)d_in[6];
  const float* b1     = (const float*)d_in[7];
  const float* wout   = (const float*)d_in[8];
  const float* bout   = (const float*)d_in[9];
  float* out = (float*)d_out;

  char* ws = (char*)d_ws;
  unsigned short* W0K = (unsigned short*)(ws + 0);          //  1.5 MB
  unsigned short* W0R = (unsigned short*)(ws + 1572864);    // 25.2 MB
  unsigned short* W1K = (unsigned short*)(ws + 26738688);   // 25.2 MB
  unsigned short* W1R = (unsigned short*)(ws + 51904512);   // 25.2 MB
  unsigned short* X   = (unsigned short*)(ws + 77070336);   //  2.6 MB
  float* H0F          = (float*)(ws + 79691776);            //  1 MB fp32 state
  float* H1F          = (float*)(ws + 80740352);            //  1 MB
  unsigned short* H0B = (unsigned short*)(ws + 81788928);   //  0.5 MB bf16 state
  unsigned short* H1B = (unsigned short*)(ws + 82313216);   //  0.5 MB
  unsigned short* G0  = (unsigned short*)(ws + 82837504);   // 13 bf16 planes (6.5 MB)
  unsigned short* G1I = (unsigned short*)(ws + 89653248);   // 12 bf16 planes (6 MB)
  unsigned short* G1R = (unsigned short*)(ws + 95944704);   // 12 bf16 planes (6 MB)
  // total ws use: 102,236,160 bytes

  // zero h state (H0F, H1F, H0B, H1B are contiguous): 3 MiB
  hipMemsetAsync(ws + 79691776, 0, 3145728, stream);

  // weight conversion to tiled bf16
  convert_w<<<384,  256, 0, stream>>>(k0, W0K, 100,  2);   // KC=4 (K padded to 128)
  convert_w<<<6144, 256, 0, stream>>>(r0, W0R, 2048, 6);   // KC=64
  convert_w<<<6144, 256, 0, stream>>>(k1, W1K, 2048, 6);
  convert_w<<<6144, 256, 0, stream>>>(r1, W1R, 2048, 6);

  // embedding gather (time-major, padded)
  embed_k<<<5120, 256, 0, stream>>>(tokens, emb, X);

  // 81 pipelined step dispatches: d computes h0(d) and h1(d-1) concurrently
  for (int d = 0; d <= TT; ++d) {
    step_gemms<<<768, 256, 0, stream>>>(d, X, W0K, W0R, W1K, W1R, H0B, H1B,
                                        G0, G1I, G1R);
    gates_k<<<256, 128, 0, stream>>>(d, G0, G1I, G1R, b0, b1,
                                     H0F, H0B, H1F, H1B);
  }

  out_k<<<128, 64, 0, stream>>>(H1F, wout, bout, out);
}

// Round 10
// 2534.408 us; speedup vs baseline: 9.1279x; 1.0704x over previous
//
#include <hip/hip_runtime.h>
#include <cstdint>
#include <cstddef>

#define BB 128    // batch
#define TT 80     // seq
#define EE 100    // emb dim
#define EP 128    // padded emb dim
#define UU 2048   // units
#define G3 6144   // 3*UU
#define PLANE (BB * UU)   // 262144 elements, one gate pre-activation plane

typedef __bf16 bf16x8 __attribute__((ext_vector_type(8)));
typedef float f32x4 __attribute__((ext_vector_type(4)));
typedef int   i32x4 __attribute__((ext_vector_type(4)));

static __device__ __forceinline__ unsigned short f2bf(float x) {
  union { float f; unsigned int u; } a; a.f = x;
  unsigned int r = a.u + 0x7fffu + ((a.u >> 16) & 1u);  // RNE
  return (unsigned short)(r >> 16);
}

static __device__ __forceinline__ float sigf(float x) {
  return 1.f / (1.f + __expf(-x));
}
static __device__ __forceinline__ float tanhfast(float x) {
  return 1.f - 2.f / (__expf(2.f * x) + 1.f);
}

// accumulate 8 bf16 plane values (one int4 load) into float[8]
static __device__ __forceinline__ void acc8(float* s, const unsigned short* p) {
  int4 v = *reinterpret_cast<const int4*>(p);
  unsigned int w0 = (unsigned int)v.x, w1 = (unsigned int)v.y,
               w2 = (unsigned int)v.z, w3 = (unsigned int)v.w;
  union { unsigned int u; float f; } c;
  c.u = w0 << 16;         s[0] += c.f;
  c.u = w0 & 0xffff0000u; s[1] += c.f;
  c.u = w1 << 16;         s[2] += c.f;
  c.u = w1 & 0xffff0000u; s[3] += c.f;
  c.u = w2 << 16;         s[4] += c.f;
  c.u = w2 & 0xffff0000u; s[5] += c.f;
  c.u = w3 << 16;         s[6] += c.f;
  c.u = w3 & 0xffff0000u; s[7] += c.f;
}

static __device__ __forceinline__ void addbias8(float* s, const float* b) {
  f32x4 x0 = *reinterpret_cast<const f32x4*>(b);
  f32x4 x1 = *reinterpret_cast<const f32x4*>(b + 4);
#pragma unroll
  for (int i = 0; i < 4; ++i) { s[i] += x0[i]; s[4 + i] += x1[i]; }
}

// per-column max -> fscale (colmax/127^2, dequant) and qinv (127/colmax, quant).
// One block per 64-column group; 96 blocks per (2048 x 6144) matrix.
__global__ __launch_bounds__(256) void colscale_k(const float* __restrict__ src,
                                                  float* __restrict__ fscale,
                                                  float* __restrict__ qinv) {
  int t = threadIdx.x;
  int col = blockIdx.x * 64 + (t & 63);
  int r0 = t >> 6;
  float m = 0.f;
  for (int k = r0; k < UU; k += 4) m = fmaxf(m, fabsf(src[(size_t)k * G3 + col]));
  __shared__ float red[256];
  red[t] = m;
  __syncthreads();
  if (t < 64) {
    m = fmaxf(fmaxf(red[t], red[t + 64]), fmaxf(red[t + 128], red[t + 192]));
    fscale[col] = m * (1.f / 16129.f);
    qinv[col] = 127.f / m;
  }
}

// fp32 (2048 x 6144) -> int8 MFMA-tiled (per-column scaled).
// group idx = gg*(128*32*64) + (ct*32 + c)*64 + L ; lane L of chunk c holds
// B[k = c*64 + (L>>4)*16 + j][col = ct*16 + (L&15)], j=0..15 (16 B contiguous).
__global__ __launch_bounds__(256) void convert_w_i8(const float* __restrict__ src,
                                                    const float* __restrict__ qinv,
                                                    signed char* __restrict__ dst) {
  int tid = blockIdx.x * 256 + threadIdx.x;   // 786432 groups
  int gg = tid >> 18;
  int rem = tid & 262143;
  int ctc = rem >> 6;          // ct*32 + c
  int L = rem & 63;
  int ct = ctc >> 5, c = ctc & 31;
  int nl = L & 15, kq = L >> 4;
  int ocol = gg * 2048 + ct * 16 + nl;
  int kbase = c * 64 + kq * 16;
  float qi = qinv[ocol];
  union { signed char b[16]; int4 v; } o;
#pragma unroll
  for (int j = 0; j < 16; ++j) {
    int k = kbase + j;
    int q = (int)rintf(src[(size_t)k * G3 + ocol] * qi);
    o.b[j] = (signed char)q;
  }
  *reinterpret_cast<int4*>(dst + (size_t)tid * 16) = o.v;
}

// Convert fp32 weight (ksrc x 6144, row-major) -> bf16 MFMA-tiled layout (W0K only).
__global__ void convert_w(const float* __restrict__ src, unsigned short* __restrict__ dst,
                          int ksrc, int kc_shift) {
  int tid = blockIdx.x * 256 + threadIdx.x;
  int nl = tid & 15;
  int kb = (tid >> 4) & 3;
  int kc_mask = (1 << kc_shift) - 1;
  int c  = (tid >> 6) & kc_mask;
  int ct = tid >> (6 + kc_shift);
  int col = ct * 16 + nl;
  int kbase = c * 32 + kb * 8;
  union { unsigned short u[8]; int4 v; } o;
#pragma unroll
  for (int j = 0; j < 8; ++j) {
    int k = kbase + j;
    float v = (k < ksrc) ? src[(size_t)k * G3 + col] : 0.f;
    o.u[j] = f2bf(v);
  }
  *reinterpret_cast<int4*>(dst + (size_t)tid * 8) = o.v;
}

// X[t][b][e] = bf16(emb[tokens[b][t]][e]), e padded to 128 with zeros.
__global__ void embed_k(const int* __restrict__ tokens, const float* __restrict__ emb,
                        unsigned short* __restrict__ X) {
  int idx = blockIdx.x * 256 + threadIdx.x;
  int e = idx & (EP - 1);
  int b = (idx >> 7) & (BB - 1);
  int t = idx >> 14;
  float v = 0.f;
  if (e < EE) {
    int tok = tokens[b * TT + t];
    v = emb[(size_t)tok * EE + e];
  }
  X[idx] = f2bf(v);
}

// Store one f32x4 acc plane as bf16: C/D layout col=lane&15, row=kq*4+reg.
static __device__ __forceinline__ void store_plane(
    unsigned short* __restrict__ G, const f32x4& a, int ct16, int mt8, int lane) {
  int col = ct16 * 16 + (lane & 15);
  int kq = lane >> 4;
#pragma unroll
  for (int r = 0; r < 4; ++r) {
    int m = mt8 * 16 + kq * 4 + r;
    G[(size_t)m * UU + col] = f2bf(a[r]);
  }
}

// Pipelined step dispatch d (0..80): 768 blocks x 256 threads, 3 blocks/CU.
// blockIdx = g*256 + kh*64 + tu.  g: 0=L0, 1=L1-input, 2=L1-recurrent.
// int8 GEMM path: v_mfma_i32_16x16x64_i8, weights per-column int8, h int8
// (scale 1/127).  int32 accumulate is exact; epilogue dequantizes with
// fscale[col]=colmax/127^2 and stores bf16 partial planes (R9 scheme).
// W-stream halves to ~37 MB/dispatch vs bf16.
__global__ __launch_bounds__(256, 3) void step_gemms(
    int d,
    const unsigned short* __restrict__ X,
    const unsigned short* __restrict__ W0K,
    const signed char* __restrict__ QW0R, const signed char* __restrict__ QW1K,
    const signed char* __restrict__ QW1R,
    const float* __restrict__ FS0R, const float* __restrict__ FS1K,
    const float* __restrict__ FS1R,
    const signed char* __restrict__ H0Q, const signed char* __restrict__ H1Q,
    unsigned short* __restrict__ G0, unsigned short* __restrict__ G1I,
    unsigned short* __restrict__ G1R) {
  int tu = blockIdx.x & 63;
  int kh = (blockIdx.x >> 6) & 3;
  int g  = blockIdx.x >> 8;
  int lane = threadIdx.x & 63;
  int wave = threadIdx.x >> 6;   // mg: rows wave*32 .. +32
  int nl = lane & 15;
  int kq = lane >> 4;

  __shared__ unsigned char sbuf[2][24576];   // 2 x 24 KB weight windows

  const signed char* Aq;
  const signed char* QW;
  const float* FS;
  if (g == 0)      { if (d >= TT) return; Aq = H0Q; QW = QW0R; FS = FS0R; }
  else if (g == 1) { if (d <  1)  return; Aq = H0Q; QW = QW1K; FS = FS1K; }
  else             { if (d <  1)  return; Aq = H1Q; QW = QW1R; FS = FS1R; }

  i32x4 acc[2][2][3];   // [mt][nt][gate] int32 accumulators
#pragma unroll
  for (int mt = 0; mt < 2; ++mt)
#pragma unroll
    for (int nt = 0; nt < 2; ++nt)
#pragma unroll
      for (int gg = 0; gg < 3; ++gg) acc[mt][nt][gg] = {0, 0, 0, 0};

  const signed char* ap[2];
#pragma unroll
  for (int mt = 0; mt < 2; ++mt)
    ap[mt] = Aq + (size_t)(wave * 32 + mt * 16 + nl) * UU + kq * 16;

  // staging map: 6 int4 per thread cover one 24 KB window (4 chunks of K=64)
  // slot = (kcw*2 + nt)*3 + gg ; window advance = 4 chunks = 4096 B
  int woff[6];
  int soff0 = threadIdx.x * 16;   // bytes; ss*16 = slot*1024 + l16*16
  {
    int t = threadIdx.x;
#pragma unroll
    for (int i = 0; i < 6; ++i) {
      int ss = i * 256 + t;
      int slot = ss >> 6, l16 = ss & 63;
      int gg = slot % 3, q = slot / 3;
      int nt = q & 1, kcw = q >> 1;
      woff[i] = gg * 4194304 + (((tu * 2 + nt) * 32 + kh * 8 + kcw) * 64 + l16) * 16;
    }
  }

  i32x4 areg[4][2];
  // prologue: A chunks (kh*8 + 0..3) first, then W window 0
#pragma unroll
  for (int kcw = 0; kcw < 4; ++kcw)
#pragma unroll
    for (int mt = 0; mt < 2; ++mt)
      areg[kcw][mt] = *reinterpret_cast<const i32x4*>(ap[mt] + (size_t)(kh * 8 + kcw) * 64);
  {
    int4 v[6];
#pragma unroll
    for (int i = 0; i < 6; ++i) v[i] = *reinterpret_cast<const int4*>(QW + (size_t)woff[i]);
#pragma unroll
    for (int i = 0; i < 6; ++i)
      *reinterpret_cast<int4*>(&sbuf[0][soff0 + i * 4096]) = v[i];
  }
  __syncthreads();

#pragma unroll
  for (int w = 0; w < 2; ++w) {
    i32x4 anext[4][2];
    int4 v[6];
    if (w == 0) {
#pragma unroll
      for (int kcw = 0; kcw < 4; ++kcw)
#pragma unroll
        for (int mt = 0; mt < 2; ++mt)
          anext[kcw][mt] = *reinterpret_cast<const i32x4*>(
              ap[mt] + (size_t)(kh * 8 + 4 + kcw) * 64);
#pragma unroll
      for (int i = 0; i < 6; ++i)
        v[i] = *reinterpret_cast<const int4*>(QW + (size_t)woff[i] + 4096);
    }
#pragma unroll
    for (int kcw = 0; kcw < 4; ++kcw) {
#pragma unroll
      for (int nt = 0; nt < 2; ++nt) {
#pragma unroll
        for (int gg = 0; gg < 3; ++gg) {
          i32x4 b = *reinterpret_cast<const i32x4*>(
              &sbuf[w & 1][((kcw * 2 + nt) * 3 + gg) * 1024 + lane * 16]);
#pragma unroll
          for (int mt = 0; mt < 2; ++mt)
            acc[mt][nt][gg] = __builtin_amdgcn_mfma_i32_16x16x64_i8(
                areg[kcw][mt], b, acc[mt][nt][gg], 0, 0, 0);
        }
      }
    }
    if (w == 0) {
#pragma unroll
      for (int i = 0; i < 6; ++i)
        *reinterpret_cast<int4*>(&sbuf[1][soff0 + i * 4096]) = v[i];
#pragma unroll
      for (int kcw = 0; kcw < 4; ++kcw)
#pragma unroll
        for (int mt = 0; mt < 2; ++mt) areg[kcw][mt] = anext[kcw][mt];
      __syncthreads();
    }
  }

  // L0 input projection (bf16, K=128 padded), kh==0 blocks, after main loop
  // so its registers don't inflate the K-loop's live set.
  f32x4 acci[2][2][2];   // [mt][nt][z/r]
  bool do_inp = (g == 0 && kh == 0);
  if (do_inp) {
#pragma unroll
    for (int nt = 0; nt < 2; ++nt) {
      const unsigned short* wp = W0K + (size_t)(tu * 2 + nt) * 4 * 512 + (size_t)lane * 8;
#pragma unroll
      for (int mt = 0; mt < 2; ++mt) {
        const unsigned short* xp = X + (size_t)d * BB * EP
                                 + (size_t)(wave * 32 + mt * 16 + nl) * EP + kq * 8;
        f32x4 t0 = {0,0,0,0}, t1 = {0,0,0,0}, t2 = {0,0,0,0};
#pragma unroll
        for (int c = 0; c < 4; ++c) {
          bf16x8 a  = *reinterpret_cast<const bf16x8*>(xp + c * 32);
          bf16x8 b0 = *reinterpret_cast<const bf16x8*>(wp + (size_t)0 * (128 * 4 * 512) + c * 512);
          bf16x8 b1 = *reinterpret_cast<const bf16x8*>(wp + (size_t)1 * (128 * 4 * 512) + c * 512);
          bf16x8 b2 = *reinterpret_cast<const bf16x8*>(wp + (size_t)2 * (128 * 4 * 512) + c * 512);
          t0 = __builtin_amdgcn_mfma_f32_16x16x32_bf16(a, b0, t0, 0, 0, 0);
          t1 = __builtin_amdgcn_mfma_f32_16x16x32_bf16(a, b1, t1, 0, 0, 0);
          t2 = __builtin_amdgcn_mfma_f32_16x16x32_bf16(a, b2, t2, 0, 0, 0);
        }
        acci[mt][nt][0] = t0;
        acci[mt][nt][1] = t1;
        store_plane(G0 + (size_t)12 * PLANE, t2, tu * 2 + nt, wave * 2 + mt, lane);
      }
    }
  }

  // epilogue: dequantize + bf16 partial planes (plane = gate*4 + kh)
#pragma unroll
  for (int mt = 0; mt < 2; ++mt) {
#pragma unroll
    for (int nt = 0; nt < 2; ++nt) {
      int ct16 = tu * 2 + nt;
      int col = ct16 * 16 + nl;
      int mt8 = wave * 2 + mt;
      float fs0 = FS[0 * UU + col], fs1 = FS[1 * UU + col], fs2 = FS[2 * UU + col];
      f32x4 p0, p1, p2;
#pragma unroll
      for (int i = 0; i < 4; ++i) {
        p0[i] = (float)acc[mt][nt][0][i] * fs0;
        p1[i] = (float)acc[mt][nt][1][i] * fs1;
        p2[i] = (float)acc[mt][nt][2][i] * fs2;
      }
      if (do_inp) { p0 += acci[mt][nt][0]; p1 += acci[mt][nt][1]; }
      unsigned short* base = (g == 0) ? G0 : (g == 1) ? G1I : G1R;
      store_plane(base + (size_t)(0 + kh) * PLANE, p0, ct16, mt8, lane);
      store_plane(base + (size_t)(4 + kh) * PLANE, p1, ct16, mt8, lane);
      store_plane(base + (size_t)(8 + kh) * PLANE, p2, ct16, mt8, lane);
    }
  }
}

// Gate math + state update for dispatch d: h0(d) [d<80] and h1(d-1) [d>=1].
// Writes fp32 state + int8 quantized state (scale 127).
__global__ __launch_bounds__(128) void gates_k(
    int d,
    const unsigned short* __restrict__ G0, const unsigned short* __restrict__ G1I,
    const unsigned short* __restrict__ G1R,
    const float* __restrict__ b0, const float* __restrict__ b1,
    float* __restrict__ H0F, signed char* __restrict__ H0Q,
    float* __restrict__ H1F, signed char* __restrict__ H1Q) {
  int t = blockIdx.x * 128 + threadIdx.x;   // 32768 threads
  size_t idx = (size_t)t * 8;
  int u = (int)(idx & (UU - 1));

  if (d < TT) {
    float zs[8] = {0,0,0,0,0,0,0,0}, rs[8] = {0,0,0,0,0,0,0,0};
    float hh[8] = {0,0,0,0,0,0,0,0}, ih[8] = {0,0,0,0,0,0,0,0};
#pragma unroll
    for (int p = 0; p < 4; ++p) {
      acc8(zs, G0 + (size_t)p * PLANE + idx);
      acc8(rs, G0 + (size_t)(4 + p) * PLANE + idx);
      acc8(hh, G0 + (size_t)(8 + p) * PLANE + idx);
    }
    acc8(ih, G0 + (size_t)12 * PLANE + idx);
    addbias8(zs, b0 + u);          addbias8(zs, b0 + G3 + u);
    addbias8(rs, b0 + UU + u);     addbias8(rs, b0 + G3 + UU + u);
    addbias8(ih, b0 + 2 * UU + u);
    addbias8(hh, b0 + G3 + 2 * UU + u);
    f32x4 h0 = *reinterpret_cast<const f32x4*>(H0F + idx);
    f32x4 h1 = *reinterpret_cast<const f32x4*>(H0F + idx + 4);
    float hold[8] = {h0[0], h0[1], h0[2], h0[3], h1[0], h1[1], h1[2], h1[3]};
    float hn[8];
#pragma unroll
    for (int i = 0; i < 8; ++i) {
      float z = sigf(zs[i]), r = sigf(rs[i]);
      float cand = tanhfast(ih[i] + r * hh[i]);
      hn[i] = z * hold[i] + (1.f - z) * cand;
    }
    unsigned int qa = 0, qb = 0;
#pragma unroll
    for (int i = 0; i < 4; ++i) {
      qa |= ((unsigned int)((int)rintf(hn[i] * 127.f) & 0xff)) << (8 * i);
      qb |= ((unsigned int)((int)rintf(hn[4 + i] * 127.f) & 0xff)) << (8 * i);
    }
    *reinterpret_cast<f32x4*>(H0F + idx)     = f32x4{hn[0], hn[1], hn[2], hn[3]};
    *reinterpret_cast<f32x4*>(H0F + idx + 4) = f32x4{hn[4], hn[5], hn[6], hn[7]};
    *reinterpret_cast<uint2*>(H0Q + idx) = make_uint2(qa, qb);
  }
  if (d >= 1) {
    float iz[8] = {0,0,0,0,0,0,0,0}, ir[8] = {0,0,0,0,0,0,0,0}, ih[8] = {0,0,0,0,0,0,0,0};
    float hz[8] = {0,0,0,0,0,0,0,0}, hr[8] = {0,0,0,0,0,0,0,0}, hh[8] = {0,0,0,0,0,0,0,0};
#pragma unroll
    for (int p = 0; p < 4; ++p) {
      acc8(iz, G1I + (size_t)p * PLANE + idx);
      acc8(ir, G1I + (size_t)(4 + p) * PLANE + idx);
      acc8(ih, G1I + (size_t)(8 + p) * PLANE + idx);
      acc8(hz, G1R + (size_t)p * PLANE + idx);
      acc8(hr, G1R + (size_t)(4 + p) * PLANE + idx);
      acc8(hh, G1R + (size_t)(8 + p) * PLANE + idx);
    }
    addbias8(iz, b1 + u);           addbias8(hz, b1 + G3 + u);
    addbias8(ir, b1 + UU + u);      addbias8(hr, b1 + G3 + UU + u);
    addbias8(ih, b1 + 2 * UU + u);  addbias8(hh, b1 + G3 + 2 * UU + u);
    f32x4 h0 = *reinterpret_cast<const f32x4*>(H1F + idx);
    f32x4 h1 = *reinterpret_cast<const f32x4*>(H1F + idx + 4);
    float hold[8] = {h0[0], h0[1], h0[2], h0[3], h1[0], h1[1], h1[2], h1[3]};
    float hn[8];
#pragma unroll
    for (int i = 0; i < 8; ++i) {
      float z = sigf(iz[i] + hz[i]), r = sigf(ir[i] + hr[i]);
      float cand = tanhfast(ih[i] + r * hh[i]);
      hn[i] = z * hold[i] + (1.f - z) * cand;
    }
    unsigned int qa = 0, qb = 0;
#pragma unroll
    for (int i = 0; i < 4; ++i) {
      qa |= ((unsigned int)((int)rintf(hn[i] * 127.f) & 0xff)) << (8 * i);
      qb |= ((unsigned int)((int)rintf(hn[4 + i] * 127.f) & 0xff)) << (8 * i);
    }
    *reinterpret_cast<f32x4*>(H1F + idx)     = f32x4{hn[0], hn[1], hn[2], hn[3]};
    *reinterpret_cast<f32x4*>(H1F + idx + 4) = f32x4{hn[4], hn[5], hn[6], hn[7]};
    *reinterpret_cast<uint2*>(H1Q + idx) = make_uint2(qa, qb);
  }
}

// logits = sigmoid(h1 @ wout + bout): 128 blocks x 64 threads, one row each.
__global__ void out_k(const float* __restrict__ h1, const float* __restrict__ wout,
                      const float* __restrict__ bout, float* __restrict__ out) {
  int row = blockIdx.x;
  int lane = threadIdx.x;
  float s = 0.f;
  for (int i = lane; i < UU; i += 64) s += h1[(size_t)row * UU + i] * wout[i];
#pragma unroll
  for (int off = 32; off > 0; off >>= 1) s += __shfl_down(s, off);
  if (lane == 0) out[row] = 1.f / (1.f + __expf(-(s + bout[0])));
}

extern "C" void kernel_launch(void* const* d_in, const int* in_sizes, int n_in,
                              void* d_out, int out_size, void* d_ws, size_t ws_size,
                              hipStream_t stream) {
  const int*   tokens = (const int*)  d_in[0];
  const float* emb    = (const float*)d_in[1];
  const float* k0     = (const float*)d_in[2];
  const float* r0     = (const float*)d_in[3];
  const float* b0     = (const float*)d_in[4];
  const float* k1     = (const float*)d_in[5];
  const float* r1     = (const float*)d_in[6];
  const float* b1     = (const float*)d_in[7];
  const float* wout   = (const float*)d_in[8];
  const float* bout   = (const float*)d_in[9];
  float* out = (float*)d_out;

  char* ws = (char*)d_ws;
  unsigned short* W0K = (unsigned short*)(ws + 0);           //  1.5 MB bf16 tiled
  signed char* QW0R   = (signed char*)(ws + 1572864);        // 12.6 MB int8 tiled
  signed char* QW1K   = (signed char*)(ws + 14155776);       // 12.6 MB
  signed char* QW1R   = (signed char*)(ws + 26738688);       // 12.6 MB
  float* FS0R         = (float*)(ws + 39321600);             // 24 KB dequant scales
  float* FS1K         = (float*)(ws + 39346176);
  float* FS1R         = (float*)(ws + 39370752);
  float* QI0R         = (float*)(ws + 39395328);             // 24 KB quant inv-scales
  float* QI1K         = (float*)(ws + 39419904);
  float* QI1R         = (float*)(ws + 39444480);
  unsigned short* X   = (unsigned short*)(ws + 39469056);    //  2.6 MB bf16
  float* H0F          = (float*)(ws + 42090496);             //  1 MB fp32 state
  float* H1F          = (float*)(ws + 43139072);             //  1 MB
  signed char* H0Q    = (signed char*)(ws + 44187648);       //  0.25 MB int8 state
  signed char* H1Q    = (signed char*)(ws + 44449792);       //  0.25 MB
  unsigned short* G0  = (unsigned short*)(ws + 44711936);    // 13 bf16 planes (6.5 MB)
  unsigned short* G1I = (unsigned short*)(ws + 51527680);    // 12 bf16 planes (6 MB)
  unsigned short* G1R = (unsigned short*)(ws + 57819136);    // 12 bf16 planes (6 MB)
  // total ws use: 64,110,592 bytes

  // zero h state (H0F, H1F, H0Q, H1Q contiguous): 2.5 MiB
  hipMemsetAsync(ws + 42090496, 0, 2621440, stream);

  // per-column scales, then int8 tiled conversion (big matrices)
  colscale_k<<<96, 256, 0, stream>>>(r0, FS0R, QI0R);
  colscale_k<<<96, 256, 0, stream>>>(k1, FS1K, QI1K);
  colscale_k<<<96, 256, 0, stream>>>(r1, FS1R, QI1R);
  convert_w_i8<<<3072, 256, 0, stream>>>(r0, QI0R, QW0R);
  convert_w_i8<<<3072, 256, 0, stream>>>(k1, QI1K, QW1K);
  convert_w_i8<<<3072, 256, 0, stream>>>(r1, QI1R, QW1R);

  // L0 input-proj weights stay bf16 (tiny, K=128 padded)
  convert_w<<<384, 256, 0, stream>>>(k0, W0K, 100, 2);

  // embedding gather (time-major, padded)
  embed_k<<<5120, 256, 0, stream>>>(tokens, emb, X);

  // 81 pipelined step dispatches: d computes h0(d) and h1(d-1) concurrently
  for (int d = 0; d <= TT; ++d) {
    step_gemms<<<768, 256, 0, stream>>>(d, X, W0K, QW0R, QW1K, QW1R,
                                        FS0R, FS1K, FS1R, H0Q, H1Q,
                                        G0, G1I, G1R);
    gates_k<<<256, 128, 0, stream>>>(d, G0, G1I, G1R, b0, b1,
                                     H0F, H0Q, H1F, H1Q);
  }

  out_k<<<128, 64, 0, stream>>>(H1F, wout, bout, out);
}